// Round 1
// baseline (3172.640 us; speedup 1.0000x reference)
//
#include <hip/hip_runtime.h>

#define BNEPS 1e-5f

// ---------------- utility kernels ----------------

__global__ void k_fill(float* p, int n, float v){
  int i = blockIdx.x*blockDim.x + threadIdx.x;
  if(i < n) p[i] = v;
}

__global__ void k_deg_scatter(float* deg, const int* dst, const float* w, int E){
  int e = blockIdx.x*blockDim.x + threadIdx.x;
  if(e < E) atomicAdd(&deg[dst[e]], w[e]);
}

__global__ void k_rsqrt_inplace(float* p, int n){
  int i = blockIdx.x*blockDim.x + threadIdx.x;
  if(i < n) p[i] = rsqrtf(p[i]);   // deg >= 1 always (self-loop weight 1)
}

__global__ void k_norm(const float* dis, const int* src, const int* dst,
                       const float* w, float* nrm, int E){
  int e = blockIdx.x*blockDim.x + threadIdx.x;
  if(e < E) nrm[e] = dis[src[e]] * w[e] * dis[dst[e]];
}

// ---------------- GEMM kernels ----------------

// layer1: X[n,4] @ W[4,64] -> H[n,64]
__global__ void k_gemm_in4(const float* __restrict__ X, const float* __restrict__ W,
                           float* __restrict__ H, int n){
  int idx = blockIdx.x*blockDim.x + threadIdx.x;
  if(idx >= n*64) return;
  int i = idx >> 6, c = idx & 63;
  float4 xr = *reinterpret_cast<const float4*>(X + i*4);
  H[idx] = xr.x*W[c] + xr.y*W[64+c] + xr.z*W[128+c] + xr.w*W[192+c];
}

// generic small GEMM: X[n,K] @ W[K,C] (+bias) -> H[n,C], K,C in {64,128}
template<int K, int C, int BR>
__global__ void k_gemm(const float* __restrict__ X, const float* __restrict__ W,
                       const float* __restrict__ bias, float* __restrict__ H, int n){
  __shared__ float Ws[K*C];
  __shared__ float Xs[BR*K];
  int tid = threadIdx.x;               // 256 threads
  for(int t = tid; t < K*C; t += 256) Ws[t] = W[t];
  int r0 = blockIdx.x * BR;
  for(int t = tid; t < BR*K; t += 256){
    int r = r0 + t / K;
    Xs[t] = (r < n) ? X[(long long)r*K + (t % K)] : 0.f;
  }
  __syncthreads();
  for(int o = tid; o < BR*C; o += 256){
    int i = o / C, c = o % C;
    int row = r0 + i;
    if(row >= n) continue;
    float acc = bias ? bias[c] : 0.f;
    #pragma unroll
    for(int k = 0; k < K; k++) acc = fmaf(Xs[i*K+k], Ws[k*C+c], acc);
    H[(long long)row*C + c] = acc;
  }
}

// ---------------- GCN aggregation ----------------

// agg[i][c] = bias[c] + H[i][c]*dis[i]^2   (self-loop term, norm = dis_i * 1 * dis_i)
template<int C>
__global__ void k_agg_init(const float* __restrict__ H, const float* __restrict__ dis,
                           const float* __restrict__ bias, float* __restrict__ agg, int n){
  int idx = blockIdx.x*blockDim.x + threadIdx.x;
  if(idx >= n*C) return;
  int i = idx / C, c = idx % C;
  float d = dis[i];
  agg[idx] = bias[c] + H[idx]*d*d;
}

// agg[dst][c] += H[src][c] * norm[e]  — one thread per (edge, 4-channel group)
template<int C>
__global__ void k_agg_edges(const float* __restrict__ H, const float* __restrict__ nrm,
                            const int* __restrict__ src, const int* __restrict__ dst,
                            float* __restrict__ agg, int E){
  const int G = C/4;
  long long idx = (long long)blockIdx.x*blockDim.x + threadIdx.x;
  if(idx >= (long long)E*G) return;
  int e = (int)(idx / G), g = (int)(idx % G);
  float nv = nrm[e];
  int s = src[e], d = dst[e];
  float4 hv = *reinterpret_cast<const float4*>(H + (long long)s*C + g*4);
  float* ap = agg + (long long)d*C + g*4;
  atomicAdd(ap+0, hv.x*nv);
  atomicAdd(ap+1, hv.y*nv);
  atomicAdd(ap+2, hv.z*nv);
  atomicAdd(ap+3, hv.w*nv);
}

// ---------------- BatchNorm (training mode, biased var) ----------------

// stats[c] += sum, stats[C+c] += sumsq  (stats must be zeroed first)
template<int C>
__global__ void k_stats(const float* __restrict__ x, int n, float* __restrict__ stats){
  __shared__ float ss[256], ss2[256];
  int tid = threadIdx.x;
  const int rpb = 256 / C;
  int c = tid % C;
  int rsub = tid / C;
  float s = 0.f, s2 = 0.f;
  for(int i = blockIdx.x*rpb + rsub; i < n; i += gridDim.x*rpb){
    float v = x[(long long)i*C + c];
    s += v; s2 += v*v;
  }
  ss[tid] = s; ss2[tid] = s2;
  __syncthreads();
  if(tid < C){
    float a = 0.f, a2 = 0.f;
    for(int j = tid; j < 256; j += C){ a += ss[j]; a2 += ss2[j]; }
    atomicAdd(&stats[c], a);
    atomicAdd(&stats[C+c], a2);
  }
}

// out = relu(bn(agg)) + add    (identity / precomputed shortcut)
template<int C>
__global__ void k_bn_apply_add(const float* __restrict__ agg, const float* __restrict__ stats,
                               const float* __restrict__ g, const float* __restrict__ be,
                               const float* __restrict__ add, float* __restrict__ out, int n){
  int idx = blockIdx.x*blockDim.x + threadIdx.x;
  if(idx >= n*C) return;
  int c = idx % C;
  float invn = 1.0f / n;
  float m  = stats[c]*invn;
  float v  = stats[C+c]*invn - m*m;
  float rs = rsqrtf(v + BNEPS);
  out[idx] = fmaxf((agg[idx]-m)*rs*g[c] + be[c], 0.f) + add[idx];
}

// block1: out = relu(bn(agg)) + x[i,0:4] @ sW + sb    (C=64)
__global__ void k_bn_apply_sc4(const float* __restrict__ agg, const float* __restrict__ stats,
                               const float* __restrict__ g, const float* __restrict__ be,
                               const float* __restrict__ X, const float* __restrict__ sW,
                               const float* __restrict__ sb, float* __restrict__ out, int n){
  int idx = blockIdx.x*blockDim.x + threadIdx.x;
  if(idx >= n*64) return;
  int i = idx >> 6, c = idx & 63;
  float invn = 1.0f / n;
  float m  = stats[c]*invn;
  float v  = stats[64+c]*invn - m*m;
  float rs = rsqrtf(v + BNEPS);
  float4 xr = *reinterpret_cast<const float4*>(X + i*4);
  float sc = xr.x*sW[c] + xr.y*sW[64+c] + xr.z*sW[128+c] + xr.w*sW[192+c] + sb[c];
  out[idx] = fmaxf((agg[idx]-m)*rs*g[c] + be[c], 0.f) + sc;
}

// ---------------- pooling ----------------

// one block per graph, 128 threads (one per channel); batch is sorted
__global__ void k_pool(const float* __restrict__ H, const int* __restrict__ batch,
                       float* __restrict__ z, int n){
  int b = blockIdx.x, c = threadIdx.x;
  int lo = 0, hi = n;
  while(lo < hi){ int mid = (lo+hi)>>1; if(batch[mid] <  b) lo = mid+1; else hi = mid; }
  int start = lo;
  hi = n;
  while(lo < hi){ int mid = (lo+hi)>>1; if(batch[mid] <  b+1) lo = mid+1; else hi = mid; }
  int end = lo;
  float s = 0.f, mx = -INFINITY;
  for(int i = start; i < end; i++){
    float v = H[(long long)i*128 + c];
    s += v; mx = fmaxf(mx, v);
  }
  int cnt = end - start;
  z[b*256 + c]       = s / fmaxf((float)cnt, 1.f);
  z[b*256 + 128 + c] = mx;
}

// ---------------- head ----------------

// zr[b][c] = z[b,0:256] @ fW1[:,c] + fb1[c]
__global__ void k_head1(const float* __restrict__ z, const float* __restrict__ fW1,
                        const float* __restrict__ fb1, float* __restrict__ zr, int B){
  int idx = blockIdx.x*blockDim.x + threadIdx.x;
  if(idx >= B*128) return;
  int b = idx >> 7, c = idx & 127;
  float acc = fb1[c];
  #pragma unroll 4
  for(int k = 0; k < 256; k++) acc = fmaf(z[b*256+k], fW1[k*128+c], acc);
  zr[idx] = acc;
}

// out[b] = sum_c relu(bn(zr[b][c]))*fW2[c] + fb2
__global__ void k_final(const float* __restrict__ zr, const float* __restrict__ stats,
                        const float* __restrict__ fg, const float* __restrict__ fbe,
                        const float* __restrict__ fW2, const float* __restrict__ fb2,
                        float* __restrict__ out, int B){
  __shared__ float red[128];
  int b = blockIdx.x, c = threadIdx.x;
  float invn = 1.0f / B;
  float m  = stats[c]*invn;
  float v  = stats[128+c]*invn - m*m;
  float rs = rsqrtf(v + BNEPS);
  float val = fmaxf((zr[b*128+c]-m)*rs*fg[c] + fbe[c], 0.f) * fW2[c];
  red[c] = val;
  __syncthreads();
  for(int s = 64; s > 0; s >>= 1){
    if(c < s) red[c] += red[c+s];
    __syncthreads();
  }
  if(c == 0) out[b] = red[0] + fb2[0];
}

// ---------------- launch ----------------

extern "C" void kernel_launch(void* const* d_in, const int* in_sizes, int n_in,
                              void* d_out, int out_size, void* d_ws, size_t ws_size,
                              hipStream_t stream){
  const float* x   = (const float*)d_in[0];
  const int*   ei  = (const int*)  d_in[1];
  const float* ew  = (const float*)d_in[2];
  const int*   bat = (const int*)  d_in[3];
  const float* W1  = (const float*)d_in[4];  const float* b1  = (const float*)d_in[5];
  const float* g1  = (const float*)d_in[6];  const float* be1 = (const float*)d_in[7];
  const float* sW1 = (const float*)d_in[8];  const float* sb1 = (const float*)d_in[9];
  const float* W2  = (const float*)d_in[10]; const float* b2  = (const float*)d_in[11];
  const float* g2  = (const float*)d_in[12]; const float* be2 = (const float*)d_in[13];
  const float* W3  = (const float*)d_in[14]; const float* b3  = (const float*)d_in[15];
  const float* g3  = (const float*)d_in[16]; const float* be3 = (const float*)d_in[17];
  const float* sW3 = (const float*)d_in[18]; const float* sb3 = (const float*)d_in[19];
  const float* fW1 = (const float*)d_in[20]; const float* fb1 = (const float*)d_in[21];
  const float* fg  = (const float*)d_in[22]; const float* fbe = (const float*)d_in[23];
  const float* fW2 = (const float*)d_in[24]; const float* fb2 = (const float*)d_in[25];
  float* out = (float*)d_out;

  const int n = in_sizes[0] / 4;
  const int E = in_sizes[2];
  const int B = out_size;          // 512
  const int* src = ei;
  const int* dst = ei + E;

  float* ws = (float*)d_ws;
  size_t off = 0;
  float* dis  = ws + off; off += (size_t)((n + 63)/64)*64;
  float* nrm  = ws + off; off += (size_t)((E + 63)/64)*64;
  float* bufA = ws + off; off += (size_t)n * 64;
  float* hbuf = ws + off; off += (size_t)n * 128;
  float* agg  = ws + off; off += (size_t)n * 128;
  float* z    = ws + off; off += (size_t)B * 256;
  float* zr   = ws + off; off += (size_t)B * 128;
  float* stats= ws + off; off += 256;

  auto GB = [](long long t){ return (int)((t + 255) / 256); };

  // degree / norm precompute
  k_fill<<<GB(n),256,0,stream>>>(dis, n, 1.0f);                    // self-loop weight
  k_deg_scatter<<<GB(E),256,0,stream>>>(dis, dst, ew, E);
  k_rsqrt_inplace<<<GB(n),256,0,stream>>>(dis, n);
  k_norm<<<GB(E),256,0,stream>>>(dis, src, dst, ew, nrm, E);

  // ---- block1: GCN(4->64) + BN + ReLU + (x@sW1+sb1) -> bufA
  k_gemm_in4<<<GB((long long)n*64),256,0,stream>>>(x, W1, hbuf, n);
  k_agg_init<64><<<GB((long long)n*64),256,0,stream>>>(hbuf, dis, b1, agg, n);
  k_agg_edges<64><<<GB((long long)E*16),256,0,stream>>>(hbuf, nrm, src, dst, agg, E);
  k_fill<<<1,256,0,stream>>>(stats, 256, 0.f);
  k_stats<64><<<256,256,0,stream>>>(agg, n, stats);
  k_bn_apply_sc4<<<GB((long long)n*64),256,0,stream>>>(agg, stats, g1, be1, x, sW1, sb1, bufA, n);

  // ---- block2: GCN(64->64) + BN + ReLU + identity -> bufA (in place)
  k_gemm<64,64,32><<<(n+31)/32,256,0,stream>>>(bufA, W2, nullptr, hbuf, n);
  k_agg_init<64><<<GB((long long)n*64),256,0,stream>>>(hbuf, dis, b2, agg, n);
  k_agg_edges<64><<<GB((long long)E*16),256,0,stream>>>(hbuf, nrm, src, dst, agg, E);
  k_fill<<<1,256,0,stream>>>(stats, 256, 0.f);
  k_stats<64><<<256,256,0,stream>>>(agg, n, stats);
  k_bn_apply_add<64><<<GB((long long)n*64),256,0,stream>>>(agg, stats, g2, be2, bufA, bufA, n);

  // ---- block3: GCN(64->128) + BN + ReLU + (bufA@sW3+sb3) -> agg (in place)
  k_gemm<64,128,16><<<(n+15)/16,256,0,stream>>>(bufA, W3, nullptr, hbuf, n);
  k_agg_init<128><<<GB((long long)n*128),256,0,stream>>>(hbuf, dis, b3, agg, n);
  k_agg_edges<128><<<GB((long long)E*32),256,0,stream>>>(hbuf, nrm, src, dst, agg, E);
  k_gemm<64,128,16><<<(n+15)/16,256,0,stream>>>(bufA, sW3, sb3, hbuf, n);   // shortcut
  k_fill<<<1,256,0,stream>>>(stats, 256, 0.f);
  k_stats<128><<<256,256,0,stream>>>(agg, n, stats);
  k_bn_apply_add<128><<<GB((long long)n*128),256,0,stream>>>(agg, stats, g3, be3, hbuf, agg, n);

  // ---- pooling: per-graph mean/max -> z[B,256]
  k_pool<<<B,128,0,stream>>>(agg, bat, z, n);

  // ---- head: Linear(256,128)+BN+ReLU+Linear(128,1)
  k_head1<<<GB((long long)B*128),256,0,stream>>>(z, fW1, fb1, zr, B);
  k_fill<<<1,256,0,stream>>>(stats, 256, 0.f);
  k_stats<128><<<64,256,0,stream>>>(zr, B, stats);
  k_final<<<B,128,0,stream>>>(zr, stats, fg, fbe, fW2, fb2, out, B);
}

// Round 2
// 821.472 us; speedup vs baseline: 3.8621x; 3.8621x over previous
//
#include <hip/hip_runtime.h>

#define BNEPS 1e-5f

// ---------------- utility kernels ----------------

__global__ void k_fill(float* p, int n, float v){
  int i = blockIdx.x*blockDim.x + threadIdx.x;
  if(i < n) p[i] = v;
}

__global__ void k_filli(int* p, int n, int v){
  int i = blockIdx.x*blockDim.x + threadIdx.x;
  if(i < n) p[i] = v;
}

// ---------------- CSR build (counting sort by dst) ----------------

__global__ void k_count(int* cnt, const int* dst, int E){
  int e = blockIdx.x*blockDim.x + threadIdx.x;
  if(e < E) atomicAdd(&cnt[dst[e]], 1);
}

// block-level exclusive scan, 256/block; writes per-block totals
__global__ void k_scan1(const int* cnt, int* rowptr, int* bsum, int n){
  __shared__ int sh[256];
  int tid = threadIdx.x;
  int i = blockIdx.x*256 + tid;
  int v = (i < n) ? cnt[i] : 0;
  sh[tid] = v;
  __syncthreads();
  for(int o = 1; o < 256; o <<= 1){
    int t = (tid >= o) ? sh[tid-o] : 0;
    __syncthreads();
    sh[tid] += t;
    __syncthreads();
  }
  if(i < n) rowptr[i] = sh[tid] - v;          // exclusive, no base
  if(tid == 255) bsum[blockIdx.x] = sh[255];  // block total
}

// exclusive scan of block sums (m <= 256), in place
__global__ void k_scan2(int* bsum, int m){
  __shared__ int sh[256];
  int tid = threadIdx.x;
  int v = (tid < m) ? bsum[tid] : 0;
  sh[tid] = v;
  __syncthreads();
  for(int o = 1; o < 256; o <<= 1){
    int t = (tid >= o) ? sh[tid-o] : 0;
    __syncthreads();
    sh[tid] += t;
    __syncthreads();
  }
  if(tid < m) bsum[tid] = sh[tid] - v;
}

__global__ void k_scan3(int* rowptr, const int* bsum, int n, int E){
  int i = blockIdx.x*blockDim.x + threadIdx.x;
  if(i < n) rowptr[i] += bsum[i >> 8];
  if(i == 0) rowptr[n] = E;
}

// sort edges by dst: ssrc/sw get src id and raw weight
__global__ void k_scatter_edges(const int* src, const int* dst, const float* w,
                                const int* rowptr, int* cur,
                                int* ssrc, float* sw, int E){
  int e = blockIdx.x*blockDim.x + threadIdx.x;
  if(e >= E) return;
  int d = dst[e];
  int idx = rowptr[d] + atomicAdd(&cur[d], 1);
  ssrc[idx] = src[e];
  sw[idx] = w[e];
}

// deg[i] = 1 + sum of incoming weights; dis = rsqrt(deg)
__global__ void k_degdis(const float* __restrict__ sw, const int* __restrict__ rowptr,
                         float* __restrict__ dis, int n){
  int i = blockIdx.x*blockDim.x + threadIdx.x;
  if(i >= n) return;
  float s = 1.0f;
  int e0 = rowptr[i], e1 = rowptr[i+1];
  for(int j = e0; j < e1; j++) s += sw[j];
  dis[i] = rsqrtf(s);
}

// sw[j] <- dis[src]*w*dis[dst]   (in place; becomes the edge norm)
__global__ void k_mknorm(float* __restrict__ sw, const int* __restrict__ ssrc,
                         const int* __restrict__ rowptr, const float* __restrict__ dis, int n){
  int i = blockIdx.x*blockDim.x + threadIdx.x;
  if(i >= n) return;
  float di = dis[i];
  int e0 = rowptr[i], e1 = rowptr[i+1];
  for(int j = e0; j < e1; j++) sw[j] = dis[ssrc[j]] * sw[j] * di;
}

// gather aggregation: agg[i][c] = bias[c] + H[i][c]*dis[i]^2 + sum_j H[ssrc[j]][c]*sw[j]
template<int C>
__global__ void k_gather(const float* __restrict__ H, const float* __restrict__ dis,
                         const int* __restrict__ rowptr, const int* __restrict__ ssrc,
                         const float* __restrict__ sw, const float* __restrict__ bias,
                         float* __restrict__ agg, int n){
  const int NPB = 256 / C;
  int i = blockIdx.x*NPB + threadIdx.x / C;
  int c = threadIdx.x % C;
  if(i >= n) return;
  float di = dis[i];
  float acc = bias[c] + H[(long long)i*C + c]*di*di;
  int e0 = rowptr[i], e1 = rowptr[i+1];
  for(int j = e0; j < e1; j++){
    acc += H[(long long)ssrc[j]*C + c] * sw[j];
  }
  agg[(long long)i*C + c] = acc;
}

// ---------------- legacy atomic-scatter path (ws fallback) ----------------

__global__ void k_deg_scatter(float* deg, const int* dst, const float* w, int E){
  int e = blockIdx.x*blockDim.x + threadIdx.x;
  if(e < E) atomicAdd(&deg[dst[e]], w[e]);
}

__global__ void k_rsqrt_inplace(float* p, int n){
  int i = blockIdx.x*blockDim.x + threadIdx.x;
  if(i < n) p[i] = rsqrtf(p[i]);
}

__global__ void k_norm(const float* dis, const int* src, const int* dst,
                       const float* w, float* nrm, int E){
  int e = blockIdx.x*blockDim.x + threadIdx.x;
  if(e < E) nrm[e] = dis[src[e]] * w[e] * dis[dst[e]];
}

template<int C>
__global__ void k_agg_init(const float* __restrict__ H, const float* __restrict__ dis,
                           const float* __restrict__ bias, float* __restrict__ agg, int n){
  int idx = blockIdx.x*blockDim.x + threadIdx.x;
  if(idx >= n*C) return;
  int i = idx / C, c = idx % C;
  float d = dis[i];
  agg[idx] = bias[c] + H[idx]*d*d;
}

template<int C>
__global__ void k_agg_edges(const float* __restrict__ H, const float* __restrict__ nrm,
                            const int* __restrict__ src, const int* __restrict__ dst,
                            float* __restrict__ agg, int E){
  const int G = C/4;
  long long idx = (long long)blockIdx.x*blockDim.x + threadIdx.x;
  if(idx >= (long long)E*G) return;
  int e = (int)(idx / G), g = (int)(idx % G);
  float nv = nrm[e];
  int s = src[e], d = dst[e];
  float4 hv = *reinterpret_cast<const float4*>(H + (long long)s*C + g*4);
  float* ap = agg + (long long)d*C + g*4;
  atomicAdd(ap+0, hv.x*nv);
  atomicAdd(ap+1, hv.y*nv);
  atomicAdd(ap+2, hv.z*nv);
  atomicAdd(ap+3, hv.w*nv);
}

// ---------------- GEMM kernels ----------------

__global__ void k_gemm_in4(const float* __restrict__ X, const float* __restrict__ W,
                           float* __restrict__ H, int n){
  int idx = blockIdx.x*blockDim.x + threadIdx.x;
  if(idx >= n*64) return;
  int i = idx >> 6, c = idx & 63;
  float4 xr = *reinterpret_cast<const float4*>(X + i*4);
  H[idx] = xr.x*W[c] + xr.y*W[64+c] + xr.z*W[128+c] + xr.w*W[192+c];
}

template<int K, int C, int BR>
__global__ void k_gemm(const float* __restrict__ X, const float* __restrict__ W,
                       const float* __restrict__ bias, float* __restrict__ H, int n){
  __shared__ float Ws[K*C];
  __shared__ float Xs[BR*K];
  int tid = threadIdx.x;               // 256 threads
  for(int t = tid; t < K*C; t += 256) Ws[t] = W[t];
  int r0 = blockIdx.x * BR;
  for(int t = tid; t < BR*K; t += 256){
    int r = r0 + t / K;
    Xs[t] = (r < n) ? X[(long long)r*K + (t % K)] : 0.f;
  }
  __syncthreads();
  for(int o = tid; o < BR*C; o += 256){
    int i = o / C, c = o % C;
    int row = r0 + i;
    if(row >= n) continue;
    float acc = bias ? bias[c] : 0.f;
    #pragma unroll
    for(int k = 0; k < K; k++) acc = fmaf(Xs[i*K+k], Ws[k*C+c], acc);
    H[(long long)row*C + c] = acc;
  }
}

// ---------------- BatchNorm ----------------

template<int C>
__global__ void k_stats(const float* __restrict__ x, int n, float* __restrict__ stats){
  __shared__ float ss[256], ss2[256];
  int tid = threadIdx.x;
  const int rpb = 256 / C;
  int c = tid % C;
  int rsub = tid / C;
  float s = 0.f, s2 = 0.f;
  for(int i = blockIdx.x*rpb + rsub; i < n; i += gridDim.x*rpb){
    float v = x[(long long)i*C + c];
    s += v; s2 += v*v;
  }
  ss[tid] = s; ss2[tid] = s2;
  __syncthreads();
  if(tid < C){
    float a = 0.f, a2 = 0.f;
    for(int j = tid; j < 256; j += C){ a += ss[j]; a2 += ss2[j]; }
    atomicAdd(&stats[c], a);
    atomicAdd(&stats[C+c], a2);
  }
}

template<int C>
__global__ void k_bn_apply_add(const float* __restrict__ agg, const float* __restrict__ stats,
                               const float* __restrict__ g, const float* __restrict__ be,
                               const float* __restrict__ add, float* __restrict__ out, int n){
  int idx = blockIdx.x*blockDim.x + threadIdx.x;
  if(idx >= n*C) return;
  int c = idx % C;
  float invn = 1.0f / n;
  float m  = stats[c]*invn;
  float v  = stats[C+c]*invn - m*m;
  float rs = rsqrtf(v + BNEPS);
  out[idx] = fmaxf((agg[idx]-m)*rs*g[c] + be[c], 0.f) + add[idx];
}

__global__ void k_bn_apply_sc4(const float* __restrict__ agg, const float* __restrict__ stats,
                               const float* __restrict__ g, const float* __restrict__ be,
                               const float* __restrict__ X, const float* __restrict__ sW,
                               const float* __restrict__ sb, float* __restrict__ out, int n){
  int idx = blockIdx.x*blockDim.x + threadIdx.x;
  if(idx >= n*64) return;
  int i = idx >> 6, c = idx & 63;
  float invn = 1.0f / n;
  float m  = stats[c]*invn;
  float v  = stats[64+c]*invn - m*m;
  float rs = rsqrtf(v + BNEPS);
  float4 xr = *reinterpret_cast<const float4*>(X + i*4);
  float sc = xr.x*sW[c] + xr.y*sW[64+c] + xr.z*sW[128+c] + xr.w*sW[192+c] + sb[c];
  out[idx] = fmaxf((agg[idx]-m)*rs*g[c] + be[c], 0.f) + sc;
}

// ---------------- pooling ----------------

__global__ void k_pool(const float* __restrict__ H, const int* __restrict__ batch,
                       float* __restrict__ z, int n){
  int b = blockIdx.x, c = threadIdx.x;
  int lo = 0, hi = n;
  while(lo < hi){ int mid = (lo+hi)>>1; if(batch[mid] <  b) lo = mid+1; else hi = mid; }
  int start = lo;
  hi = n;
  while(lo < hi){ int mid = (lo+hi)>>1; if(batch[mid] <  b+1) lo = mid+1; else hi = mid; }
  int end = lo;
  float s = 0.f, mx = -INFINITY;
  for(int i = start; i < end; i++){
    float v = H[(long long)i*128 + c];
    s += v; mx = fmaxf(mx, v);
  }
  int cnt = end - start;
  z[b*256 + c]       = s / fmaxf((float)cnt, 1.f);
  z[b*256 + 128 + c] = mx;
}

// ---------------- head ----------------

__global__ void k_head1(const float* __restrict__ z, const float* __restrict__ fW1,
                        const float* __restrict__ fb1, float* __restrict__ zr, int B){
  int idx = blockIdx.x*blockDim.x + threadIdx.x;
  if(idx >= B*128) return;
  int b = idx >> 7, c = idx & 127;
  float acc = fb1[c];
  #pragma unroll 4
  for(int k = 0; k < 256; k++) acc = fmaf(z[b*256+k], fW1[k*128+c], acc);
  zr[idx] = acc;
}

__global__ void k_final(const float* __restrict__ zr, const float* __restrict__ stats,
                        const float* __restrict__ fg, const float* __restrict__ fbe,
                        const float* __restrict__ fW2, const float* __restrict__ fb2,
                        float* __restrict__ out, int B){
  __shared__ float red[128];
  int b = blockIdx.x, c = threadIdx.x;
  float invn = 1.0f / B;
  float m  = stats[c]*invn;
  float v  = stats[128+c]*invn - m*m;
  float rs = rsqrtf(v + BNEPS);
  float val = fmaxf((zr[b*128+c]-m)*rs*fg[c] + fbe[c], 0.f) * fW2[c];
  red[c] = val;
  __syncthreads();
  for(int s = 64; s > 0; s >>= 1){
    if(c < s) red[c] += red[c+s];
    __syncthreads();
  }
  if(c == 0) out[b] = red[0] + fb2[0];
}

// ---------------- launch ----------------

extern "C" void kernel_launch(void* const* d_in, const int* in_sizes, int n_in,
                              void* d_out, int out_size, void* d_ws, size_t ws_size,
                              hipStream_t stream){
  const float* x   = (const float*)d_in[0];
  const int*   ei  = (const int*)  d_in[1];
  const float* ew  = (const float*)d_in[2];
  const int*   bat = (const int*)  d_in[3];
  const float* W1  = (const float*)d_in[4];  const float* b1  = (const float*)d_in[5];
  const float* g1  = (const float*)d_in[6];  const float* be1 = (const float*)d_in[7];
  const float* sW1 = (const float*)d_in[8];  const float* sb1 = (const float*)d_in[9];
  const float* W2  = (const float*)d_in[10]; const float* b2  = (const float*)d_in[11];
  const float* g2  = (const float*)d_in[12]; const float* be2 = (const float*)d_in[13];
  const float* W3  = (const float*)d_in[14]; const float* b3  = (const float*)d_in[15];
  const float* g3  = (const float*)d_in[16]; const float* be3 = (const float*)d_in[17];
  const float* sW3 = (const float*)d_in[18]; const float* sb3 = (const float*)d_in[19];
  const float* fW1 = (const float*)d_in[20]; const float* fb1 = (const float*)d_in[21];
  const float* fg  = (const float*)d_in[22]; const float* fbe = (const float*)d_in[23];
  const float* fW2 = (const float*)d_in[24]; const float* fb2 = (const float*)d_in[25];
  float* out = (float*)d_out;

  const int n = in_sizes[0] / 4;
  const int E = in_sizes[2];
  const int B = out_size;          // 512
  const int* src = ei;
  const int* dst = ei + E;

  auto GB = [](long long t){ return (int)((t + 255) / 256); };
  const int nscanb = (n + 255) / 256;   // <= 256 required for k_scan2

  float* ws = (float*)d_ws;
  size_t off = 0;
  auto alloc = [&](size_t cnt)->float*{ float* p = ws + off; off += (cnt + 63) & ~size_t(63); return p; };

  // shared allocations
  float* dis  = alloc(n);
  float* bufA = alloc((size_t)n * 64);
  float* hbuf = alloc((size_t)n * 128);
  float* agg  = alloc((size_t)n * 128);
  float* z    = alloc((size_t)B * 256);
  float* zr   = alloc((size_t)B * 128);
  float* stats= alloc(256);
  size_t shared_off = off;

  // CSR-path extras
  int*   rowptr = (int*)alloc(n + 1);
  int*   cur    = (int*)alloc(n);
  int*   bsum   = (int*)alloc(256);
  int*   ssrc   = (int*)alloc(E);
  float* sw     = alloc(E);
  size_t need_csr = off * 4;

  bool use_csr = (ws_size >= need_csr);

  if(use_csr){
    // ---- build CSR (sorted by dst) ----
    k_filli<<<GB(n),256,0,stream>>>(cur, n, 0);
    k_count<<<GB(E),256,0,stream>>>(cur, dst, E);
    k_scan1<<<nscanb,256,0,stream>>>(cur, rowptr, bsum, n);
    k_scan2<<<1,256,0,stream>>>(bsum, nscanb);
    k_scan3<<<GB(n),256,0,stream>>>(rowptr, bsum, n, E);
    k_filli<<<GB(n),256,0,stream>>>(cur, n, 0);
    k_scatter_edges<<<GB(E),256,0,stream>>>(src, dst, ew, rowptr, cur, ssrc, sw, E);
    k_degdis<<<GB(n),256,0,stream>>>(sw, rowptr, dis, n);
    k_mknorm<<<GB(n),256,0,stream>>>(sw, ssrc, rowptr, dis, n);

    // ---- block1: GCN(4->64)+BN+ReLU+(x@sW1+sb1) -> bufA
    k_gemm_in4<<<GB((long long)n*64),256,0,stream>>>(x, W1, hbuf, n);
    k_gather<64><<<(n+3)/4,256,0,stream>>>(hbuf, dis, rowptr, ssrc, sw, b1, agg, n);
    k_fill<<<1,256,0,stream>>>(stats, 256, 0.f);
    k_stats<64><<<256,256,0,stream>>>(agg, n, stats);
    k_bn_apply_sc4<<<GB((long long)n*64),256,0,stream>>>(agg, stats, g1, be1, x, sW1, sb1, bufA, n);

    // ---- block2: GCN(64->64)+BN+ReLU+identity -> bufA
    k_gemm<64,64,32><<<(n+31)/32,256,0,stream>>>(bufA, W2, nullptr, hbuf, n);
    k_gather<64><<<(n+3)/4,256,0,stream>>>(hbuf, dis, rowptr, ssrc, sw, b2, agg, n);
    k_fill<<<1,256,0,stream>>>(stats, 256, 0.f);
    k_stats<64><<<256,256,0,stream>>>(agg, n, stats);
    k_bn_apply_add<64><<<GB((long long)n*64),256,0,stream>>>(agg, stats, g2, be2, bufA, bufA, n);

    // ---- block3: GCN(64->128)+BN+ReLU+(bufA@sW3+sb3) -> agg
    k_gemm<64,128,16><<<(n+15)/16,256,0,stream>>>(bufA, W3, nullptr, hbuf, n);
    k_gather<128><<<(n+1)/2,256,0,stream>>>(hbuf, dis, rowptr, ssrc, sw, b3, agg, n);
    k_gemm<64,128,16><<<(n+15)/16,256,0,stream>>>(bufA, sW3, sb3, hbuf, n);   // shortcut
    k_fill<<<1,256,0,stream>>>(stats, 256, 0.f);
    k_stats<128><<<256,256,0,stream>>>(agg, n, stats);
    k_bn_apply_add<128><<<GB((long long)n*128),256,0,stream>>>(agg, stats, g3, be3, hbuf, agg, n);
  } else {
    // ---- legacy atomic path (smaller ws footprint) ----
    off = shared_off;
    float* nrm = alloc(E);

    k_fill<<<GB(n),256,0,stream>>>(dis, n, 1.0f);
    k_deg_scatter<<<GB(E),256,0,stream>>>(dis, dst, ew, E);
    k_rsqrt_inplace<<<GB(n),256,0,stream>>>(dis, n);
    k_norm<<<GB(E),256,0,stream>>>(dis, src, dst, ew, nrm, E);

    k_gemm_in4<<<GB((long long)n*64),256,0,stream>>>(x, W1, hbuf, n);
    k_agg_init<64><<<GB((long long)n*64),256,0,stream>>>(hbuf, dis, b1, agg, n);
    k_agg_edges<64><<<GB((long long)E*16),256,0,stream>>>(hbuf, nrm, src, dst, agg, E);
    k_fill<<<1,256,0,stream>>>(stats, 256, 0.f);
    k_stats<64><<<256,256,0,stream>>>(agg, n, stats);
    k_bn_apply_sc4<<<GB((long long)n*64),256,0,stream>>>(agg, stats, g1, be1, x, sW1, sb1, bufA, n);

    k_gemm<64,64,32><<<(n+31)/32,256,0,stream>>>(bufA, W2, nullptr, hbuf, n);
    k_agg_init<64><<<GB((long long)n*64),256,0,stream>>>(hbuf, dis, b2, agg, n);
    k_agg_edges<64><<<GB((long long)E*16),256,0,stream>>>(hbuf, nrm, src, dst, agg, E);
    k_fill<<<1,256,0,stream>>>(stats, 256, 0.f);
    k_stats<64><<<256,256,0,stream>>>(agg, n, stats);
    k_bn_apply_add<64><<<GB((long long)n*64),256,0,stream>>>(agg, stats, g2, be2, bufA, bufA, n);

    k_gemm<64,128,16><<<(n+15)/16,256,0,stream>>>(bufA, W3, nullptr, hbuf, n);
    k_agg_init<128><<<GB((long long)n*128),256,0,stream>>>(hbuf, dis, b3, agg, n);
    k_agg_edges<128><<<GB((long long)E*32),256,0,stream>>>(hbuf, nrm, src, dst, agg, E);
    k_gemm<64,128,16><<<(n+15)/16,256,0,stream>>>(bufA, sW3, sb3, hbuf, n);
    k_fill<<<1,256,0,stream>>>(stats, 256, 0.f);
    k_stats<128><<<256,256,0,stream>>>(agg, n, stats);
    k_bn_apply_add<128><<<GB((long long)n*128),256,0,stream>>>(agg, stats, g3, be3, hbuf, agg, n);
  }

  // ---- pooling + head ----
  k_pool<<<B,128,0,stream>>>(agg, bat, z, n);
  k_head1<<<GB((long long)B*128),256,0,stream>>>(z, fW1, fb1, zr, B);
  k_fill<<<1,256,0,stream>>>(stats, 256, 0.f);
  k_stats<128><<<64,256,0,stream>>>(zr, B, stats);
  k_final<<<B,128,0,stream>>>(zr, stats, fg, fbe, fW2, fb2, out, B);
}

// Round 3
// 574.284 us; speedup vs baseline: 5.5245x; 1.4304x over previous
//
#include <hip/hip_runtime.h>

#define BNEPS 1e-5f

// ---------------- utility ----------------

__global__ void k_fill(float* p, int n, float v){
  int i = blockIdx.x*blockDim.x + threadIdx.x;
  if(i < n) p[i] = v;
}

__global__ void k_filli(int* p, int n, int v){
  int i = blockIdx.x*blockDim.x + threadIdx.x;
  if(i < n) p[i] = v;
}

// ---------------- CSR build (counting sort by dst) ----------------

__global__ void k_count(int* cnt, const int* dst, int E){
  int e = blockIdx.x*blockDim.x + threadIdx.x;
  if(e < E) atomicAdd(&cnt[dst[e]], 1);
}

__global__ void k_scan1(const int* cnt, int* rowptr, int* bsum, int n){
  __shared__ int sh[256];
  int tid = threadIdx.x;
  int i = blockIdx.x*256 + tid;
  int v = (i < n) ? cnt[i] : 0;
  sh[tid] = v;
  __syncthreads();
  for(int o = 1; o < 256; o <<= 1){
    int t = (tid >= o) ? sh[tid-o] : 0;
    __syncthreads();
    sh[tid] += t;
    __syncthreads();
  }
  if(i < n) rowptr[i] = sh[tid] - v;
  if(tid == 255) bsum[blockIdx.x] = sh[255];
}

__global__ void k_scan2(int* bsum, int m){
  __shared__ int sh[256];
  int tid = threadIdx.x;
  int v = (tid < m) ? bsum[tid] : 0;
  sh[tid] = v;
  __syncthreads();
  for(int o = 1; o < 256; o <<= 1){
    int t = (tid >= o) ? sh[tid-o] : 0;
    __syncthreads();
    sh[tid] += t;
    __syncthreads();
  }
  if(tid < m) bsum[tid] = sh[tid] - v;
}

__global__ void k_scan3(int* rowptr, const int* bsum, int n, int E){
  int i = blockIdx.x*blockDim.x + threadIdx.x;
  if(i < n) rowptr[i] += bsum[i >> 8];
  if(i == 0) rowptr[n] = E;
}

__global__ void k_scatter_edges(const int* src, const int* dst, const float* w,
                                const int* rowptr, int* cur,
                                int* ssrc, float* sw, int E){
  int e = blockIdx.x*blockDim.x + threadIdx.x;
  if(e >= E) return;
  int d = dst[e];
  int idx = rowptr[d] + atomicAdd(&cur[d], 1);
  ssrc[idx] = src[e];
  sw[idx] = w[e];
}

__global__ void k_degdis(const float* __restrict__ sw, const int* __restrict__ rowptr,
                         float* __restrict__ dis, int n){
  int i = blockIdx.x*blockDim.x + threadIdx.x;
  if(i >= n) return;
  float s = 1.0f;                       // self-loop weight
  int e0 = rowptr[i], e1 = rowptr[i+1];
  for(int j = e0; j < e1; j++) s += sw[j];
  dis[i] = rsqrtf(s);
}

__global__ void k_mknorm(float* __restrict__ sw, const int* __restrict__ ssrc,
                         const int* __restrict__ rowptr, const float* __restrict__ dis, int n){
  int i = blockIdx.x*blockDim.x + threadIdx.x;
  if(i >= n) return;
  float di = dis[i];
  int e0 = rowptr[i], e1 = rowptr[i+1];
  for(int j = e0; j < e1; j++) sw[j] = dis[ssrc[j]] * sw[j] * di;
}

// ---------------- gathers (aggregate BEFORE the GEMM) ----------------

// 4-channel gather on raw x: one thread per node, float4 rows, unroll 4
__global__ void k_gather4(const float* __restrict__ X, const float* __restrict__ dis,
                          const int* __restrict__ rowptr, const int* __restrict__ ssrc,
                          const float* __restrict__ sw, float* __restrict__ P, int n){
  int i = blockIdx.x*blockDim.x + threadIdx.x;
  if(i >= n) return;
  float di = dis[i];
  float d2 = di*di;
  float4 xr = *reinterpret_cast<const float4*>(X + (size_t)i*4);
  float4 acc = make_float4(xr.x*d2, xr.y*d2, xr.z*d2, xr.w*d2);
  int e0 = rowptr[i], e1 = rowptr[i+1];
  int j = e0;
  for(; j + 4 <= e1; j += 4){
    int s0 = ssrc[j], s1 = ssrc[j+1], s2 = ssrc[j+2], s3 = ssrc[j+3];
    float w0 = sw[j], w1 = sw[j+1], w2 = sw[j+2], w3 = sw[j+3];
    float4 a = *reinterpret_cast<const float4*>(X + (size_t)s0*4);
    float4 b = *reinterpret_cast<const float4*>(X + (size_t)s1*4);
    float4 c = *reinterpret_cast<const float4*>(X + (size_t)s2*4);
    float4 d = *reinterpret_cast<const float4*>(X + (size_t)s3*4);
    acc.x += a.x*w0 + b.x*w1 + c.x*w2 + d.x*w3;
    acc.y += a.y*w0 + b.y*w1 + c.y*w2 + d.y*w3;
    acc.z += a.z*w0 + b.z*w1 + c.z*w2 + d.z*w3;
    acc.w += a.w*w0 + b.w*w1 + c.w*w2 + d.w*w3;
  }
  for(; j < e1; j++){
    float w = sw[j];
    float4 a = *reinterpret_cast<const float4*>(X + (size_t)ssrc[j]*4);
    acc.x += a.x*w; acc.y += a.y*w; acc.z += a.z*w; acc.w += a.w*w;
  }
  *reinterpret_cast<float4*>(P + (size_t)i*4) = acc;
}

// C-channel gather: one 64-lane group per node (C=64), unroll 4 for MLP latency
template<int C>
__global__ void k_gather(const float* __restrict__ H, const float* __restrict__ dis,
                         const int* __restrict__ rowptr, const int* __restrict__ ssrc,
                         const float* __restrict__ sw, float* __restrict__ P, int n){
  const int NPB = 256 / C;
  int i = blockIdx.x*NPB + threadIdx.x / C;
  int c = threadIdx.x % C;
  if(i >= n) return;
  float di = dis[i];
  float acc = H[(size_t)i*C + c]*di*di;
  int e0 = rowptr[i], e1 = rowptr[i+1];
  int j = e0;
  for(; j + 4 <= e1; j += 4){
    int s0 = ssrc[j], s1 = ssrc[j+1], s2 = ssrc[j+2], s3 = ssrc[j+3];
    float w0 = sw[j], w1 = sw[j+1], w2 = sw[j+2], w3 = sw[j+3];
    float h0 = H[(size_t)s0*C + c];
    float h1 = H[(size_t)s1*C + c];
    float h2 = H[(size_t)s2*C + c];
    float h3 = H[(size_t)s3*C + c];
    acc += h0*w0 + h1*w1 + h2*w2 + h3*w3;
  }
  for(; j < e1; j++) acc += H[(size_t)ssrc[j]*C + c] * sw[j];
  P[(size_t)i*C + c] = acc;
}

// ---------------- GEMMs ----------------

// P[n,4] @ W[4,64] + b -> H[n,64]
__global__ void k_gemm_in4(const float* __restrict__ X, const float* __restrict__ W,
                           const float* __restrict__ bias, float* __restrict__ H, int n){
  int idx = blockIdx.x*blockDim.x + threadIdx.x;
  if(idx >= n*64) return;
  int i = idx >> 6, c = idx & 63;
  float4 xr = *reinterpret_cast<const float4*>(X + (size_t)i*4);
  H[idx] = bias[c] + xr.x*W[c] + xr.y*W[64+c] + xr.z*W[128+c] + xr.w*W[192+c];
}

// X[n,K] @ W[K,C] (+bias) -> H[n,C]
template<int K, int C, int BR>
__global__ void k_gemm(const float* __restrict__ X, const float* __restrict__ W,
                       const float* __restrict__ bias, float* __restrict__ H, int n){
  __shared__ float Ws[K*C];
  __shared__ float Xs[BR*K];
  int tid = threadIdx.x;               // 256 threads
  for(int t = tid; t < K*C; t += 256) Ws[t] = W[t];
  int r0 = blockIdx.x * BR;
  for(int t = tid; t < BR*K; t += 256){
    int r = r0 + t / K;
    Xs[t] = (r < n) ? X[(size_t)r*K + (t % K)] : 0.f;
  }
  __syncthreads();
  for(int o = tid; o < BR*C; o += 256){
    int i = o / C, c = o % C;
    int row = r0 + i;
    if(row >= n) continue;
    float acc = bias ? bias[c] : 0.f;
    #pragma unroll
    for(int k = 0; k < K; k++) acc = fmaf(Xs[i*K+k], Ws[k*C+c], acc);
    H[(size_t)row*C + c] = acc;
  }
}

// out = relu(bn(agg)) + X@sW+sb   (fused shortcut GEMM + BN epilogue)
template<int K, int C, int BR>
__global__ void k_gemm_bn_sc(const float* __restrict__ X, const float* __restrict__ sW,
                             const float* __restrict__ sb,
                             const float* __restrict__ agg, const float* __restrict__ stats,
                             const float* __restrict__ g, const float* __restrict__ be,
                             float* __restrict__ out, int n){
  __shared__ float Ws[K*C];
  __shared__ float Xs[BR*K];
  int tid = threadIdx.x;
  for(int t = tid; t < K*C; t += 256) Ws[t] = sW[t];
  int r0 = blockIdx.x * BR;
  for(int t = tid; t < BR*K; t += 256){
    int r = r0 + t / K;
    Xs[t] = (r < n) ? X[(size_t)r*K + (t % K)] : 0.f;
  }
  __syncthreads();
  float invn = 1.0f / n;
  for(int o = tid; o < BR*C; o += 256){
    int i = o / C, c = o % C;
    int row = r0 + i;
    if(row >= n) continue;
    float acc = sb[c];
    #pragma unroll
    for(int k = 0; k < K; k++) acc = fmaf(Xs[i*K+k], Ws[k*C+c], acc);
    float m  = stats[c]*invn;
    float v  = stats[C+c]*invn - m*m;
    float rs = rsqrtf(v + BNEPS);
    float a  = agg[(size_t)row*C + c];
    out[(size_t)row*C + c] = fmaxf((a-m)*rs*g[c] + be[c], 0.f) + acc;
  }
}

// ---------------- BatchNorm stats / apply ----------------

template<int C>
__global__ void k_stats(const float* __restrict__ x, int n, float* __restrict__ stats){
  __shared__ float ss[256], ss2[256];
  int tid = threadIdx.x;
  const int rpb = 256 / C;
  int c = tid % C;
  int rsub = tid / C;
  float s = 0.f, s2 = 0.f;
  for(int i = blockIdx.x*rpb + rsub; i < n; i += gridDim.x*rpb){
    float v = x[(size_t)i*C + c];
    s += v; s2 += v*v;
  }
  ss[tid] = s; ss2[tid] = s2;
  __syncthreads();
  if(tid < C){
    float a = 0.f, a2 = 0.f;
    for(int j = tid; j < 256; j += C){ a += ss[j]; a2 += ss2[j]; }
    atomicAdd(&stats[c], a);
    atomicAdd(&stats[C+c], a2);
  }
}

template<int C>
__global__ void k_bn_apply_add(const float* __restrict__ agg, const float* __restrict__ stats,
                               const float* __restrict__ g, const float* __restrict__ be,
                               const float* __restrict__ add, float* __restrict__ out, int n){
  int idx = blockIdx.x*blockDim.x + threadIdx.x;
  if(idx >= n*C) return;
  int c = idx % C;
  float invn = 1.0f / n;
  float m  = stats[c]*invn;
  float v  = stats[C+c]*invn - m*m;
  float rs = rsqrtf(v + BNEPS);
  out[idx] = fmaxf((agg[idx]-m)*rs*g[c] + be[c], 0.f) + add[idx];
}

// block1: out = relu(bn(agg)) + x[i,0:4]@sW + sb
__global__ void k_bn_apply_sc4(const float* __restrict__ agg, const float* __restrict__ stats,
                               const float* __restrict__ g, const float* __restrict__ be,
                               const float* __restrict__ X, const float* __restrict__ sW,
                               const float* __restrict__ sb, float* __restrict__ out, int n){
  int idx = blockIdx.x*blockDim.x + threadIdx.x;
  if(idx >= n*64) return;
  int i = idx >> 6, c = idx & 63;
  float invn = 1.0f / n;
  float m  = stats[c]*invn;
  float v  = stats[64+c]*invn - m*m;
  float rs = rsqrtf(v + BNEPS);
  float4 xr = *reinterpret_cast<const float4*>(X + (size_t)i*4);
  float sc = xr.x*sW[c] + xr.y*sW[64+c] + xr.z*sW[128+c] + xr.w*sW[192+c] + sb[c];
  out[idx] = fmaxf((agg[idx]-m)*rs*g[c] + be[c], 0.f) + sc;
}

// ---------------- pooling / head ----------------

__global__ void k_pool(const float* __restrict__ H, const int* __restrict__ batch,
                       float* __restrict__ z, int n){
  int b = blockIdx.x, c = threadIdx.x;
  int lo = 0, hi = n;
  while(lo < hi){ int mid = (lo+hi)>>1; if(batch[mid] <  b) lo = mid+1; else hi = mid; }
  int start = lo;
  hi = n;
  while(lo < hi){ int mid = (lo+hi)>>1; if(batch[mid] <  b+1) lo = mid+1; else hi = mid; }
  int end = lo;
  float s = 0.f, mx = -INFINITY;
  for(int i = start; i < end; i++){
    float v = H[(size_t)i*128 + c];
    s += v; mx = fmaxf(mx, v);
  }
  int cnt = end - start;
  z[b*256 + c]       = s / fmaxf((float)cnt, 1.f);
  z[b*256 + 128 + c] = mx;
}

__global__ void k_head1(const float* __restrict__ z, const float* __restrict__ fW1,
                        const float* __restrict__ fb1, float* __restrict__ zr, int B){
  int idx = blockIdx.x*blockDim.x + threadIdx.x;
  if(idx >= B*128) return;
  int b = idx >> 7, c = idx & 127;
  float acc = fb1[c];
  #pragma unroll 4
  for(int k = 0; k < 256; k++) acc = fmaf(z[b*256+k], fW1[k*128+c], acc);
  zr[idx] = acc;
}

__global__ void k_final(const float* __restrict__ zr, const float* __restrict__ stats,
                        const float* __restrict__ fg, const float* __restrict__ fbe,
                        const float* __restrict__ fW2, const float* __restrict__ fb2,
                        float* __restrict__ out, int B){
  __shared__ float red[128];
  int b = blockIdx.x, c = threadIdx.x;
  float invn = 1.0f / B;
  float m  = stats[c]*invn;
  float v  = stats[128+c]*invn - m*m;
  float rs = rsqrtf(v + BNEPS);
  float val = fmaxf((zr[b*128+c]-m)*rs*fg[c] + fbe[c], 0.f) * fW2[c];
  red[c] = val;
  __syncthreads();
  for(int s = 64; s > 0; s >>= 1){
    if(c < s) red[c] += red[c+s];
    __syncthreads();
  }
  if(c == 0) out[b] = red[0] + fb2[0];
}

// ---------------- launch ----------------

extern "C" void kernel_launch(void* const* d_in, const int* in_sizes, int n_in,
                              void* d_out, int out_size, void* d_ws, size_t ws_size,
                              hipStream_t stream){
  const float* x   = (const float*)d_in[0];
  const int*   ei  = (const int*)  d_in[1];
  const float* ew  = (const float*)d_in[2];
  const int*   bat = (const int*)  d_in[3];
  const float* W1  = (const float*)d_in[4];  const float* b1  = (const float*)d_in[5];
  const float* g1  = (const float*)d_in[6];  const float* be1 = (const float*)d_in[7];
  const float* sW1 = (const float*)d_in[8];  const float* sb1 = (const float*)d_in[9];
  const float* W2  = (const float*)d_in[10]; const float* b2  = (const float*)d_in[11];
  const float* g2  = (const float*)d_in[12]; const float* be2 = (const float*)d_in[13];
  const float* W3  = (const float*)d_in[14]; const float* b3  = (const float*)d_in[15];
  const float* g3  = (const float*)d_in[16]; const float* be3 = (const float*)d_in[17];
  const float* sW3 = (const float*)d_in[18]; const float* sb3 = (const float*)d_in[19];
  const float* fW1 = (const float*)d_in[20]; const float* fb1 = (const float*)d_in[21];
  const float* fg  = (const float*)d_in[22]; const float* fbe = (const float*)d_in[23];
  const float* fW2 = (const float*)d_in[24]; const float* fb2 = (const float*)d_in[25];
  float* out = (float*)d_out;

  const int n = in_sizes[0] / 4;
  const int E = in_sizes[2];
  const int B = out_size;          // 512
  const int* src = ei;
  const int* dst = ei + E;

  auto GB = [](long long t){ return (int)((t + 255) / 256); };
  const int nscanb = (n + 255) / 256;   // <= 256 required for k_scan2

  float* ws = (float*)d_ws;
  size_t off = 0;
  auto alloc = [&](size_t cnt)->float*{ float* p = ws + off; off += (cnt + 63) & ~size_t(63); return p; };

  float* dis   = alloc(n);
  float* bufA  = alloc((size_t)n * 64);    // block outputs (64ch)
  float* hbuf  = alloc((size_t)n * 128);   // P buffers / final block3 output
  float* agg   = alloc((size_t)n * 128);
  float* z     = alloc((size_t)B * 256);
  float* zr    = alloc((size_t)B * 128);
  float* stats = alloc(1024);              // 4 regions of 256
  float* st1 = stats, *st2 = stats+256, *st3 = stats+512, *stH = stats+768;
  int*   rowptr = (int*)alloc(n + 1);
  int*   cur    = (int*)alloc(n);
  int*   bsum   = (int*)alloc(256);
  int*   ssrc   = (int*)alloc(E);
  float* sw     = alloc(E);

  // ---- CSR build (sorted by dst), norm folded into sw ----
  k_filli<<<GB(n),256,0,stream>>>(cur, n, 0);
  k_count<<<GB(E),256,0,stream>>>(cur, dst, E);
  k_scan1<<<nscanb,256,0,stream>>>(cur, rowptr, bsum, n);
  k_scan2<<<1,256,0,stream>>>(bsum, nscanb);
  k_scan3<<<GB(n),256,0,stream>>>(rowptr, bsum, n, E);
  k_filli<<<GB(n),256,0,stream>>>(cur, n, 0);
  k_scatter_edges<<<GB(E),256,0,stream>>>(src, dst, ew, rowptr, cur, ssrc, sw, E);
  k_degdis<<<GB(n),256,0,stream>>>(sw, rowptr, dis, n);
  k_mknorm<<<GB(n),256,0,stream>>>(sw, ssrc, rowptr, dis, n);
  k_fill<<<4,256,0,stream>>>(stats, 1024, 0.f);

  // ---- block1: P1=gather(x)[n,4]; agg=P1@W1+b1; BN+ReLU+(x@sW1+sb1) -> bufA
  float* P = hbuf;   // P1 uses hbuf region
  k_gather4<<<GB(n),256,0,stream>>>(x, dis, rowptr, ssrc, sw, P, n);
  k_gemm_in4<<<GB((long long)n*64),256,0,stream>>>(P, W1, b1, agg, n);
  k_stats<64><<<256,256,0,stream>>>(agg, n, st1);
  k_bn_apply_sc4<<<GB((long long)n*64),256,0,stream>>>(agg, st1, g1, be1, x, sW1, sb1, bufA, n);

  // ---- block2: P2=gather(bufA)[n,64]; agg=P2@W2+b2; BN+ReLU+identity -> bufA
  k_gather<64><<<(n+3)/4,256,0,stream>>>(bufA, dis, rowptr, ssrc, sw, P, n);
  k_gemm<64,64,32><<<(n+31)/32,256,0,stream>>>(P, W2, b2, agg, n);
  k_stats<64><<<256,256,0,stream>>>(agg, n, st2);
  k_bn_apply_add<64><<<GB((long long)n*64),256,0,stream>>>(agg, st2, g2, be2, bufA, bufA, n);

  // ---- block3: P3=gather(bufA)[n,64]; agg=P3@W3+b3 [n,128];
  //      out = relu(bn(agg)) + bufA@sW3+sb3 -> hbuf
  k_gather<64><<<(n+3)/4,256,0,stream>>>(bufA, dis, rowptr, ssrc, sw, P, n);
  k_gemm<64,128,16><<<(n+15)/16,256,0,stream>>>(P, W3, b3, agg, n);
  k_stats<128><<<256,256,0,stream>>>(agg, n, st3);
  k_gemm_bn_sc<64,128,16><<<(n+15)/16,256,0,stream>>>(bufA, sW3, sb3, agg, st3, g3, be3, hbuf, n);

  // ---- pooling + head ----
  k_pool<<<B,128,0,stream>>>(hbuf, bat, z, n);
  k_head1<<<GB((long long)B*128),256,0,stream>>>(z, fW1, fb1, zr, B);
  k_stats<128><<<64,256,0,stream>>>(zr, B, stH);
  k_final<<<B,128,0,stream>>>(zr, stH, fg, fbe, fW2, fb2, out, B);
}

// Round 5
// 536.039 us; speedup vs baseline: 5.9187x; 1.0713x over previous
//
#include <hip/hip_runtime.h>

#define BNEPS 1e-5f

// ---------------- utility ----------------

__global__ void k_fill(float* p, int n, float v){
  int i = blockIdx.x*blockDim.x + threadIdx.x;
  if(i < n) p[i] = v;
}

// ---------------- CSR build (counting sort by dst) ----------------

__global__ void k_count(int* cnt, const int* dst, int E){
  int e = blockIdx.x*blockDim.x + threadIdx.x;
  if(e < E) atomicAdd(&cnt[dst[e]], 1);
}

// exclusive scan of cnt into rowptr; zeroes cnt for reuse as cursor
__global__ void k_scan1(int* cnt, int* rowptr, int* bsum, int n){
  __shared__ int sh[256];
  int tid = threadIdx.x;
  int i = blockIdx.x*256 + tid;
  int v = (i < n) ? cnt[i] : 0;
  sh[tid] = v;
  __syncthreads();
  for(int o = 1; o < 256; o <<= 1){
    int t = (tid >= o) ? sh[tid-o] : 0;
    __syncthreads();
    sh[tid] += t;
    __syncthreads();
  }
  if(i < n){ rowptr[i] = sh[tid] - v; cnt[i] = 0; }   // reset cursor
  if(tid == 255) bsum[blockIdx.x] = sh[255];
}

__global__ void k_scan2(int* bsum, int m){
  __shared__ int sh[256];
  int tid = threadIdx.x;
  int v = (tid < m) ? bsum[tid] : 0;
  sh[tid] = v;
  __syncthreads();
  for(int o = 1; o < 256; o <<= 1){
    int t = (tid >= o) ? sh[tid-o] : 0;
    __syncthreads();
    sh[tid] += t;
    __syncthreads();
  }
  if(tid < m) bsum[tid] = sh[tid] - v;
}

__global__ void k_scan3(int* rowptr, const int* bsum, int n, int E){
  int i = blockIdx.x*blockDim.x + threadIdx.x;
  if(i < n) rowptr[i] += bsum[i >> 8];
  if(i == 0) rowptr[n] = E;
}

// sort edges by dst into packed int2 records {src, bits(w)}
__global__ void k_scatter2(const int* __restrict__ src, const int* __restrict__ dst,
                           const float* __restrict__ w, const int* __restrict__ rowptr,
                           int* cur, int2* __restrict__ erec, int E){
  int e = blockIdx.x*blockDim.x + threadIdx.x;
  if(e >= E) return;
  int d = dst[e];
  int idx = rowptr[d] + atomicAdd(&cur[d], 1);
  erec[idx] = make_int2(src[e], __float_as_int(w[e]));
}

__global__ void k_degdis(const int2* __restrict__ erec, const int* __restrict__ rowptr,
                         float* __restrict__ dis, int n){
  int i = blockIdx.x*blockDim.x + threadIdx.x;
  if(i >= n) return;
  float s = 1.0f;                       // self-loop weight
  int e0 = rowptr[i], e1 = rowptr[i+1];
  for(int j = e0; j < e1; j++) s += __int_as_float(erec[j].y);
  dis[i] = rsqrtf(s);
}

// erec[j].w <- dis[src]*w*dis[dst]
__global__ void k_mknorm(int2* __restrict__ erec, const int* __restrict__ rowptr,
                         const float* __restrict__ dis, int n){
  int i = blockIdx.x*blockDim.x + threadIdx.x;
  if(i >= n) return;
  float di = dis[i];
  int e0 = rowptr[i], e1 = rowptr[i+1];
  for(int j = e0; j < e1; j++){
    int2 r = erec[j];
    erec[j].y = __float_as_int(dis[r.x] * __int_as_float(r.y) * di);
  }
}

// ---------------- gathers (aggregate BEFORE the GEMM) ----------------

// 4-channel gather on raw x
__global__ void k_gather4(const float* __restrict__ X, const float* __restrict__ dis,
                          const int* __restrict__ rowptr, const int2* __restrict__ erec,
                          float* __restrict__ P, int n){
  int i = blockIdx.x*blockDim.x + threadIdx.x;
  if(i >= n) return;
  float di = dis[i];
  float d2 = di*di;
  float4 xr = *reinterpret_cast<const float4*>(X + (size_t)i*4);
  float4 acc = make_float4(xr.x*d2, xr.y*d2, xr.z*d2, xr.w*d2);
  int e0 = rowptr[i], e1 = rowptr[i+1];
  int j = e0;
  for(; j + 4 <= e1; j += 4){
    int2 r0 = erec[j], r1 = erec[j+1], r2 = erec[j+2], r3 = erec[j+3];
    float w0 = __int_as_float(r0.y), w1 = __int_as_float(r1.y);
    float w2 = __int_as_float(r2.y), w3 = __int_as_float(r3.y);
    float4 a = *reinterpret_cast<const float4*>(X + (size_t)r0.x*4);
    float4 b = *reinterpret_cast<const float4*>(X + (size_t)r1.x*4);
    float4 c = *reinterpret_cast<const float4*>(X + (size_t)r2.x*4);
    float4 d = *reinterpret_cast<const float4*>(X + (size_t)r3.x*4);
    acc.x += a.x*w0 + b.x*w1 + c.x*w2 + d.x*w3;
    acc.y += a.y*w0 + b.y*w1 + c.y*w2 + d.y*w3;
    acc.z += a.z*w0 + b.z*w1 + c.z*w2 + d.z*w3;
    acc.w += a.w*w0 + b.w*w1 + c.w*w2 + d.w*w3;
  }
  for(; j < e1; j++){
    int2 r = erec[j];
    float w = __int_as_float(r.y);
    float4 a = *reinterpret_cast<const float4*>(X + (size_t)r.x*4);
    acc.x += a.x*w; acc.y += a.y*w; acc.z += a.z*w; acc.w += a.w*w;
  }
  *reinterpret_cast<float4*>(P + (size_t)i*4) = acc;
}

// 64-channel gather: one wave per node, unroll 8
template<int C>
__global__ void k_gather(const float* __restrict__ H, const float* __restrict__ dis,
                         const int* __restrict__ rowptr, const int2* __restrict__ erec,
                         float* __restrict__ P, int n){
  const int NPB = 256 / C;
  int i = blockIdx.x*NPB + threadIdx.x / C;
  int c = threadIdx.x % C;
  if(i >= n) return;
  float di = dis[i];
  float acc = H[(size_t)i*C + c]*di*di;
  int e0 = rowptr[i], e1 = rowptr[i+1];
  int j = e0;
  for(; j + 8 <= e1; j += 8){
    int2 r0 = erec[j],   r1 = erec[j+1], r2 = erec[j+2], r3 = erec[j+3];
    int2 r4 = erec[j+4], r5 = erec[j+5], r6 = erec[j+6], r7 = erec[j+7];
    float h0 = H[(size_t)r0.x*C + c];
    float h1 = H[(size_t)r1.x*C + c];
    float h2 = H[(size_t)r2.x*C + c];
    float h3 = H[(size_t)r3.x*C + c];
    float h4 = H[(size_t)r4.x*C + c];
    float h5 = H[(size_t)r5.x*C + c];
    float h6 = H[(size_t)r6.x*C + c];
    float h7 = H[(size_t)r7.x*C + c];
    acc += h0*__int_as_float(r0.y) + h1*__int_as_float(r1.y)
         + h2*__int_as_float(r2.y) + h3*__int_as_float(r3.y)
         + h4*__int_as_float(r4.y) + h5*__int_as_float(r5.y)
         + h6*__int_as_float(r6.y) + h7*__int_as_float(r7.y);
  }
  for(; j < e1; j++){
    int2 r = erec[j];
    acc += H[(size_t)r.x*C + c] * __int_as_float(r.y);
  }
  P[(size_t)i*C + c] = acc;
}

// ---------------- GEMMs (with fused BN-stats accumulation) ----------------

// P[n,4] @ W[4,64] + b -> H[n,64]; accumulates sum/sumsq into stats[0..127]
__global__ void k_gemm_in4_st(const float* __restrict__ P, const float* __restrict__ W,
                              const float* __restrict__ bias, float* __restrict__ H,
                              float* __restrict__ stats, int n){
  int tid = threadIdx.x;
  int c = tid & 63;
  float s = 0.f, s2 = 0.f;
  for(int i = blockIdx.x*4 + (tid >> 6); i < n; i += gridDim.x*4){
    float4 xr = *reinterpret_cast<const float4*>(P + (size_t)i*4);
    float acc = bias[c] + xr.x*W[c] + xr.y*W[64+c] + xr.z*W[128+c] + xr.w*W[192+c];
    H[(size_t)i*64 + c] = acc;
    s += acc; s2 += acc*acc;
  }
  __shared__ float rs[256], rs2[256];
  rs[tid] = s; rs2[tid] = s2;
  __syncthreads();
  if(tid < 64){
    float a = rs[tid] + rs[tid+64] + rs[tid+128] + rs[tid+192];
    float a2 = rs2[tid] + rs2[tid+64] + rs2[tid+128] + rs2[tid+192];
    atomicAdd(&stats[tid], a);
    atomicAdd(&stats[64+tid], a2);
  }
}

// X[n,K] @ W[K,C] + b -> H[n,C]; grid-stride over row-blocks; fused stats
template<int K, int C, int BR>
__global__ void k_gemm_st(const float* __restrict__ X, const float* __restrict__ W,
                          const float* __restrict__ bias, float* __restrict__ H,
                          float* __restrict__ stats, int n, int nrb){
  __shared__ float Ws[K*C];
  __shared__ float Xs[BR*K];
  int tid = threadIdx.x;               // 256 threads; 256%C==0
  const int c = tid % C;
  for(int t = tid; t < K*C; t += 256) Ws[t] = W[t];
  float s = 0.f, s2 = 0.f;
  float bc = bias[c];
  for(int rb = blockIdx.x; rb < nrb; rb += gridDim.x){
    int r0 = rb * BR;
    __syncthreads();
    for(int t = tid; t < BR*K; t += 256){
      int r = r0 + t / K;
      Xs[t] = (r < n) ? X[(size_t)r*K + (t % K)] : 0.f;
    }
    __syncthreads();
    for(int o = tid; o < BR*C; o += 256){
      int i = o / C;
      int row = r0 + i;
      if(row >= n) continue;
      float acc = bc;
      #pragma unroll
      for(int k = 0; k < K; k++) acc = fmaf(Xs[i*K+k], Ws[k*C+c], acc);
      H[(size_t)row*C + c] = acc;
      s += acc; s2 += acc*acc;
    }
  }
  __shared__ float rs[256], rs2[256];
  __syncthreads();
  rs[tid] = s; rs2[tid] = s2;
  __syncthreads();
  if(tid < C){
    float a = 0.f, a2 = 0.f;
    for(int j = tid; j < 256; j += C){ a += rs[j]; a2 += rs2[j]; }
    atomicAdd(&stats[tid], a);
    atomicAdd(&stats[C+tid], a2);
  }
}

// out = relu(bn(agg)) + X@sW+sb   (fused shortcut GEMM + BN epilogue)
template<int K, int C, int BR>
__global__ void k_gemm_bn_sc(const float* __restrict__ X, const float* __restrict__ sW,
                             const float* __restrict__ sb,
                             const float* __restrict__ agg, const float* __restrict__ stats,
                             const float* __restrict__ g, const float* __restrict__ be,
                             float* __restrict__ out, int n){
  __shared__ float Ws[K*C];
  __shared__ float Xs[BR*K];
  int tid = threadIdx.x;
  for(int t = tid; t < K*C; t += 256) Ws[t] = sW[t];
  int r0 = blockIdx.x * BR;
  for(int t = tid; t < BR*K; t += 256){
    int r = r0 + t / K;
    Xs[t] = (r < n) ? X[(size_t)r*K + (t % K)] : 0.f;
  }
  __syncthreads();
  float invn = 1.0f / n;
  for(int o = tid; o < BR*C; o += 256){
    int i = o / C, c = o % C;
    int row = r0 + i;
    if(row >= n) continue;
    float acc = sb[c];
    #pragma unroll
    for(int k = 0; k < K; k++) acc = fmaf(Xs[i*K+k], Ws[k*C+c], acc);
    float m  = stats[c]*invn;
    float v  = stats[C+c]*invn - m*m;
    float rs = rsqrtf(v + BNEPS);
    float a  = agg[(size_t)row*C + c];
    out[(size_t)row*C + c] = fmaxf((a-m)*rs*g[c] + be[c], 0.f) + acc;
  }
}

// ---------------- BN apply ----------------

template<int C>
__global__ void k_bn_apply_add(const float* __restrict__ agg, const float* __restrict__ stats,
                               const float* __restrict__ g, const float* __restrict__ be,
                               const float* __restrict__ add, float* __restrict__ out, int n){
  int idx = blockIdx.x*blockDim.x + threadIdx.x;
  if(idx >= n*C) return;
  int c = idx % C;
  float invn = 1.0f / n;
  float m  = stats[c]*invn;
  float v  = stats[C+c]*invn - m*m;
  float rs = rsqrtf(v + BNEPS);
  out[idx] = fmaxf((agg[idx]-m)*rs*g[c] + be[c], 0.f) + add[idx];
}

__global__ void k_bn_apply_sc4(const float* __restrict__ agg, const float* __restrict__ stats,
                               const float* __restrict__ g, const float* __restrict__ be,
                               const float* __restrict__ X, const float* __restrict__ sW,
                               const float* __restrict__ sb, float* __restrict__ out, int n){
  int idx = blockIdx.x*blockDim.x + threadIdx.x;
  if(idx >= n*64) return;
  int i = idx >> 6, c = idx & 63;
  float invn = 1.0f / n;
  float m  = stats[c]*invn;
  float v  = stats[64+c]*invn - m*m;
  float rs = rsqrtf(v + BNEPS);
  float4 xr = *reinterpret_cast<const float4*>(X + (size_t)i*4);
  float sc = xr.x*sW[c] + xr.y*sW[64+c] + xr.z*sW[128+c] + xr.w*sW[192+c] + sb[c];
  out[idx] = fmaxf((agg[idx]-m)*rs*g[c] + be[c], 0.f) + sc;
}

// ---------------- stats (head only) ----------------

template<int C>
__global__ void k_stats(const float* __restrict__ x, int n, float* __restrict__ stats){
  __shared__ float ss[256], ss2[256];
  int tid = threadIdx.x;
  const int rpb = 256 / C;
  int c = tid % C;
  int rsub = tid / C;
  float s = 0.f, s2 = 0.f;
  for(int i = blockIdx.x*rpb + rsub; i < n; i += gridDim.x*rpb){
    float v = x[(size_t)i*C + c];
    s += v; s2 += v*v;
  }
  ss[tid] = s; ss2[tid] = s2;
  __syncthreads();
  if(tid < C){
    float a = 0.f, a2 = 0.f;
    for(int j = tid; j < 256; j += C){ a += ss[j]; a2 += ss2[j]; }
    atomicAdd(&stats[c], a);
    atomicAdd(&stats[C+c], a2);
  }
}

// ---------------- pooling / head ----------------

__global__ void k_pool(const float* __restrict__ H, const int* __restrict__ batch,
                       float* __restrict__ z, int n){
  int b = blockIdx.x, c = threadIdx.x;
  int lo = 0, hi = n;
  while(lo < hi){ int mid = (lo+hi)>>1; if(batch[mid] <  b) lo = mid+1; else hi = mid; }
  int start = lo;
  hi = n;
  while(lo < hi){ int mid = (lo+hi)>>1; if(batch[mid] <  b+1) lo = mid+1; else hi = mid; }
  int end = lo;
  float s = 0.f, mx = -INFINITY;
  for(int i = start; i < end; i++){
    float v = H[(size_t)i*128 + c];
    s += v; mx = fmaxf(mx, v);
  }
  int cnt = end - start;
  z[b*256 + c]       = s / fmaxf((float)cnt, 1.f);
  z[b*256 + 128 + c] = mx;
}

__global__ void k_head1(const float* __restrict__ z, const float* __restrict__ fW1,
                        const float* __restrict__ fb1, float* __restrict__ zr, int B){
  int idx = blockIdx.x*blockDim.x + threadIdx.x;
  if(idx >= B*128) return;
  int b = idx >> 7, c = idx & 127;
  float acc = fb1[c];
  #pragma unroll 4
  for(int k = 0; k < 256; k++) acc = fmaf(z[b*256+k], fW1[k*128+c], acc);
  zr[idx] = acc;
}

__global__ void k_final(const float* __restrict__ zr, const float* __restrict__ stats,
                        const float* __restrict__ fg, const float* __restrict__ fbe,
                        const float* __restrict__ fW2, const float* __restrict__ fb2,
                        float* __restrict__ out, int B){
  __shared__ float red[128];
  int b = blockIdx.x, c = threadIdx.x;
  float invn = 1.0f / B;
  float m  = stats[c]*invn;
  float v  = stats[128+c]*invn - m*m;
  float rs = rsqrtf(v + BNEPS);
  float val = fmaxf((zr[b*128+c]-m)*rs*fg[c] + fbe[c], 0.f) * fW2[c];
  red[c] = val;
  __syncthreads();
  for(int s = 64; s > 0; s >>= 1){
    if(c < s) red[c] += red[c+s];
    __syncthreads();
  }
  if(c == 0) out[b] = red[0] + fb2[0];
}

// ---------------- launch ----------------

extern "C" void kernel_launch(void* const* d_in, const int* in_sizes, int n_in,
                              void* d_out, int out_size, void* d_ws, size_t ws_size,
                              hipStream_t stream){
  const float* x   = (const float*)d_in[0];
  const int*   ei  = (const int*)  d_in[1];
  const float* ew  = (const float*)d_in[2];
  const int*   bat = (const int*)  d_in[3];
  const float* W1  = (const float*)d_in[4];  const float* b1  = (const float*)d_in[5];
  const float* g1  = (const float*)d_in[6];  const float* be1 = (const float*)d_in[7];
  const float* sW1 = (const float*)d_in[8];  const float* sb1 = (const float*)d_in[9];
  const float* W2  = (const float*)d_in[10]; const float* b2  = (const float*)d_in[11];
  const float* g2  = (const float*)d_in[12]; const float* be2 = (const float*)d_in[13];
  const float* W3  = (const float*)d_in[14]; const float* b3  = (const float*)d_in[15];
  const float* g3  = (const float*)d_in[16]; const float* be3 = (const float*)d_in[17];
  const float* sW3 = (const float*)d_in[18]; const float* sb3 = (const float*)d_in[19];
  const float* fW1 = (const float*)d_in[20]; const float* fb1 = (const float*)d_in[21];
  const float* fg  = (const float*)d_in[22]; const float* fbe = (const float*)d_in[23];
  const float* fW2 = (const float*)d_in[24]; const float* fb2 = (const float*)d_in[25];
  float* out = (float*)d_out;

  const int n = in_sizes[0] / 4;
  const int E = in_sizes[2];
  const int B = out_size;          // 512
  const int* src = ei;
  const int* dst = ei + E;

  auto GB = [](long long t){ return (int)((t + 255) / 256); };
  const int nscanb = (n + 255) / 256;   // <= 256 required for k_scan2

  float* ws = (float*)d_ws;
  size_t off = 0;
  auto alloc = [&](size_t cnt)->float*{ float* p = ws + off; off += (cnt + 63) & ~size_t(63); return p; };

  const size_t npad = ((size_t)n + 63) & ~size_t(63);
  float* dis   = alloc(n);
  float* bufA  = alloc((size_t)n * 64);
  float* hbuf  = alloc((size_t)n * 128);   // P buffers / block3 output
  float* agg   = alloc((size_t)n * 128);
  float* z     = alloc((size_t)B * 256);
  float* zr    = alloc((size_t)B * 128);
  float* zreg  = alloc(npad + 1024);       // cnt (n ints) + 4x256 stats, zeroed together
  int*   cnt   = (int*)zreg;
  float* st1 = zreg + npad, *st2 = st1 + 256, *st3 = st2 + 256, *stH = st3 + 256;
  int*   rowptr = (int*)alloc(n + 1);
  int*   bsum   = (int*)alloc(256);
  int2*  erec   = (int2*)alloc((size_t)E * 2);

  // ---- CSR build (sorted by dst), norm folded into erec.w ----
  k_fill<<<GB(npad + 1024),256,0,stream>>>(zreg, (int)(npad + 1024), 0.f);
  k_count<<<GB(E),256,0,stream>>>(cnt, dst, E);
  k_scan1<<<nscanb,256,0,stream>>>(cnt, rowptr, bsum, n);   // also re-zeroes cnt
  k_scan2<<<1,256,0,stream>>>(bsum, nscanb);
  k_scan3<<<GB(n),256,0,stream>>>(rowptr, bsum, n, E);
  k_scatter2<<<GB(E),256,0,stream>>>(src, dst, ew, rowptr, cnt, erec, E);
  k_degdis<<<GB(n),256,0,stream>>>(erec, rowptr, dis, n);
  k_mknorm<<<GB(n),256,0,stream>>>(erec, rowptr, dis, n);

  // ---- block1: P1=gather(x)[n,4]; agg=P1@W1+b1 (+stats); BN+ReLU+(x@sW1+sb1) -> bufA
  float* P = hbuf;
  k_gather4<<<GB(n),256,0,stream>>>(x, dis, rowptr, erec, P, n);
  k_gemm_in4_st<<<512,256,0,stream>>>(P, W1, b1, agg, st1, n);
  k_bn_apply_sc4<<<GB((long long)n*64),256,0,stream>>>(agg, st1, g1, be1, x, sW1, sb1, bufA, n);

  // ---- block2: P2=gather(bufA)[n,64]; agg=P2@W2+b2 (+stats); BN+ReLU+identity -> bufA
  k_gather<64><<<(n+3)/4,256,0,stream>>>(bufA, dis, rowptr, erec, P, n);
  k_gemm_st<64,64,32><<<512,256,0,stream>>>(P, W2, b2, agg, st2, n, (n+31)/32);
  k_bn_apply_add<64><<<GB((long long)n*64),256,0,stream>>>(agg, st2, g2, be2, bufA, bufA, n);

  // ---- block3: P3=gather(bufA)[n,64]; agg=P3@W3+b3 [n,128] (+stats);
  //      out = relu(bn(agg)) + bufA@sW3+sb3 -> hbuf
  k_gather<64><<<(n+3)/4,256,0,stream>>>(bufA, dis, rowptr, erec, P, n);
  k_gemm_st<64,128,16><<<512,256,0,stream>>>(P, W3, b3, agg, st3, n, (n+15)/16);
  k_gemm_bn_sc<64,128,16><<<(n+15)/16,256,0,stream>>>(bufA, sW3, sb3, agg, st3, g3, be3, hbuf, n);

  // ---- pooling + head ----
  k_pool<<<B,128,0,stream>>>(hbuf, bat, z, n);
  k_head1<<<GB((long long)B*128),256,0,stream>>>(z, fW1, fb1, zr, B);
  k_stats<128><<<64,256,0,stream>>>(zr, B, stH);
  k_final<<<B,128,0,stream>>>(zr, stH, fg, fbe, fW2, fb2, out, B);
}

// Round 6
// 516.881 us; speedup vs baseline: 6.1381x; 1.0371x over previous
//
#include <hip/hip_runtime.h>

#define BNEPS 1e-5f

// ---------------- utility ----------------

__global__ void k_fill(float* p, int n, float v){
  int i = blockIdx.x*blockDim.x + threadIdx.x;
  if(i < n) p[i] = v;
}

// ---------------- CSR build (counting sort by dst) ----------------

__global__ void k_count(int* cnt, const int* dst, int E){
  int e = blockIdx.x*blockDim.x + threadIdx.x;
  if(e < E) atomicAdd(&cnt[dst[e]], 1);
}

// exclusive scan of cnt into rowptr; zeroes cnt for reuse as cursor
__global__ void k_scan1(int* cnt, int* rowptr, int* bsum, int n){
  __shared__ int sh[256];
  int tid = threadIdx.x;
  int i = blockIdx.x*256 + tid;
  int v = (i < n) ? cnt[i] : 0;
  sh[tid] = v;
  __syncthreads();
  for(int o = 1; o < 256; o <<= 1){
    int t = (tid >= o) ? sh[tid-o] : 0;
    __syncthreads();
    sh[tid] += t;
    __syncthreads();
  }
  if(i < n){ rowptr[i] = sh[tid] - v; cnt[i] = 0; }   // reset cursor
  if(tid == 255) bsum[blockIdx.x] = sh[255];
}

__global__ void k_scan2(int* bsum, int m){
  __shared__ int sh[256];
  int tid = threadIdx.x;
  int v = (tid < m) ? bsum[tid] : 0;
  sh[tid] = v;
  __syncthreads();
  for(int o = 1; o < 256; o <<= 1){
    int t = (tid >= o) ? sh[tid-o] : 0;
    __syncthreads();
    sh[tid] += t;
    __syncthreads();
  }
  if(tid < m) bsum[tid] = sh[tid] - v;
}

__global__ void k_scan3(int* rowptr, const int* bsum, int n, int E){
  int i = blockIdx.x*blockDim.x + threadIdx.x;
  if(i < n) rowptr[i] += bsum[i >> 8];
  if(i == 0) rowptr[n] = E;
}

// sort edges by dst into packed int2 records {src, bits(w)}
__global__ void k_scatter2(const int* __restrict__ src, const int* __restrict__ dst,
                           const float* __restrict__ w, const int* __restrict__ rowptr,
                           int* cur, int2* __restrict__ erec, int E){
  int e = blockIdx.x*blockDim.x + threadIdx.x;
  if(e >= E) return;
  int d = dst[e];
  int idx = rowptr[d] + atomicAdd(&cur[d], 1);
  erec[idx] = make_int2(src[e], __float_as_int(w[e]));
}

__global__ void k_degdis(const int2* __restrict__ erec, const int* __restrict__ rowptr,
                         float* __restrict__ dis, int n){
  int i = blockIdx.x*blockDim.x + threadIdx.x;
  if(i >= n) return;
  float s = 1.0f;                       // self-loop weight
  int e0 = rowptr[i], e1 = rowptr[i+1];
  for(int j = e0; j < e1; j++) s += __int_as_float(erec[j].y);
  dis[i] = rsqrtf(s);
}

// erec[j].w <- dis[src]*w*dis[dst]
__global__ void k_mknorm(int2* __restrict__ erec, const int* __restrict__ rowptr,
                         const float* __restrict__ dis, int n){
  int i = blockIdx.x*blockDim.x + threadIdx.x;
  if(i >= n) return;
  float di = dis[i];
  int e0 = rowptr[i], e1 = rowptr[i+1];
  for(int j = e0; j < e1; j++){
    int2 r = erec[j];
    erec[j].y = __float_as_int(dis[r.x] * __int_as_float(r.y) * di);
  }
}

// ---------------- gathers (aggregate BEFORE the GEMM) ----------------

__global__ void k_gather4(const float* __restrict__ X, const float* __restrict__ dis,
                          const int* __restrict__ rowptr, const int2* __restrict__ erec,
                          float* __restrict__ P, int n){
  int i = blockIdx.x*blockDim.x + threadIdx.x;
  if(i >= n) return;
  float di = dis[i];
  float d2 = di*di;
  float4 xr = *reinterpret_cast<const float4*>(X + (size_t)i*4);
  float4 acc = make_float4(xr.x*d2, xr.y*d2, xr.z*d2, xr.w*d2);
  int e0 = rowptr[i], e1 = rowptr[i+1];
  int j = e0;
  for(; j + 4 <= e1; j += 4){
    int2 r0 = erec[j], r1 = erec[j+1], r2 = erec[j+2], r3 = erec[j+3];
    float w0 = __int_as_float(r0.y), w1 = __int_as_float(r1.y);
    float w2 = __int_as_float(r2.y), w3 = __int_as_float(r3.y);
    float4 a = *reinterpret_cast<const float4*>(X + (size_t)r0.x*4);
    float4 b = *reinterpret_cast<const float4*>(X + (size_t)r1.x*4);
    float4 c = *reinterpret_cast<const float4*>(X + (size_t)r2.x*4);
    float4 d = *reinterpret_cast<const float4*>(X + (size_t)r3.x*4);
    acc.x += a.x*w0 + b.x*w1 + c.x*w2 + d.x*w3;
    acc.y += a.y*w0 + b.y*w1 + c.y*w2 + d.y*w3;
    acc.z += a.z*w0 + b.z*w1 + c.z*w2 + d.z*w3;
    acc.w += a.w*w0 + b.w*w1 + c.w*w2 + d.w*w3;
  }
  for(; j < e1; j++){
    int2 r = erec[j];
    float w = __int_as_float(r.y);
    float4 a = *reinterpret_cast<const float4*>(X + (size_t)r.x*4);
    acc.x += a.x*w; acc.y += a.y*w; acc.z += a.z*w; acc.w += a.w*w;
  }
  *reinterpret_cast<float4*>(P + (size_t)i*4) = acc;
}

// 64-channel gather: one wave per node, unroll 8
template<int C>
__global__ void k_gather(const float* __restrict__ H, const float* __restrict__ dis,
                         const int* __restrict__ rowptr, const int2* __restrict__ erec,
                         float* __restrict__ P, int n){
  const int NPB = 256 / C;
  int i = blockIdx.x*NPB + threadIdx.x / C;
  int c = threadIdx.x % C;
  if(i >= n) return;
  float di = dis[i];
  float acc = H[(size_t)i*C + c]*di*di;
  int e0 = rowptr[i], e1 = rowptr[i+1];
  int j = e0;
  for(; j + 8 <= e1; j += 8){
    int2 r0 = erec[j],   r1 = erec[j+1], r2 = erec[j+2], r3 = erec[j+3];
    int2 r4 = erec[j+4], r5 = erec[j+5], r6 = erec[j+6], r7 = erec[j+7];
    float h0 = H[(size_t)r0.x*C + c];
    float h1 = H[(size_t)r1.x*C + c];
    float h2 = H[(size_t)r2.x*C + c];
    float h3 = H[(size_t)r3.x*C + c];
    float h4 = H[(size_t)r4.x*C + c];
    float h5 = H[(size_t)r5.x*C + c];
    float h6 = H[(size_t)r6.x*C + c];
    float h7 = H[(size_t)r7.x*C + c];
    acc += h0*__int_as_float(r0.y) + h1*__int_as_float(r1.y)
         + h2*__int_as_float(r2.y) + h3*__int_as_float(r3.y)
         + h4*__int_as_float(r4.y) + h5*__int_as_float(r5.y)
         + h6*__int_as_float(r6.y) + h7*__int_as_float(r7.y);
  }
  for(; j < e1; j++){
    int2 r = erec[j];
    acc += H[(size_t)r.x*C + c] * __int_as_float(r.y);
  }
  P[(size_t)i*C + c] = acc;
}

// ---------------- register-weight GEMMs (K=64) ----------------

// X[n,64] @ W[64,C] + b -> H[n,C]; W column per thread in VGPRs; X staged in
// LDS, read as float4 wave-broadcast. Fused BN-stats. RPT rows per thread.
template<int C, int RPT>
__global__ __launch_bounds__(256)
void k_gemm_rw(const float* __restrict__ X, const float* __restrict__ W,
               const float* __restrict__ bias, float* __restrict__ H,
               float* __restrict__ stats, int n, int nrb){
  const int G = 256 / C;          // row groups per block
  const int TR = G * RPT;         // rows per tile
  __shared__ float4 Xs[TR*16];
  __shared__ float rs[256], rs2[256];
  int tid = threadIdx.x;
  int c = tid % C;
  int rg = tid / C;
  float w[64];
  #pragma unroll
  for(int k = 0; k < 64; k++) w[k] = W[k*C + c];
  float bc = bias[c];
  float s = 0.f, s2 = 0.f;
  const float4* X4 = reinterpret_cast<const float4*>(X);
  for(int rb = blockIdx.x; rb < nrb; rb += gridDim.x){
    int r0 = rb*TR;
    __syncthreads();
    for(int t = tid; t < TR*16; t += 256){
      int r = r0 + (t >> 4);
      Xs[t] = (r < n) ? X4[(size_t)r*16 + (t & 15)] : make_float4(0.f,0.f,0.f,0.f);
    }
    __syncthreads();
    #pragma unroll
    for(int rr = 0; rr < RPT; rr++){
      int lr = rg*RPT + rr;
      int row = r0 + lr;
      if(row >= n) continue;
      float acc = bc;
      #pragma unroll
      for(int kq = 0; kq < 16; kq++){
        float4 xv = Xs[lr*16 + kq];
        acc = fmaf(xv.x, w[4*kq+0], acc);
        acc = fmaf(xv.y, w[4*kq+1], acc);
        acc = fmaf(xv.z, w[4*kq+2], acc);
        acc = fmaf(xv.w, w[4*kq+3], acc);
      }
      H[(size_t)row*C + c] = acc;
      s += acc; s2 += acc*acc;
    }
  }
  __syncthreads();
  rs[tid] = s; rs2[tid] = s2;
  __syncthreads();
  if(tid < C){
    float a = 0.f, a2 = 0.f;
    for(int j = tid; j < 256; j += C){ a += rs[j]; a2 += rs2[j]; }
    atomicAdd(&stats[tid], a);
    atomicAdd(&stats[C+tid], a2);
  }
}

// out = relu(bn(agg)) + X@sW+sb  — register-weight shortcut GEMM + BN epilogue
template<int C, int RPT>
__global__ __launch_bounds__(256)
void k_gemm_bnsc_rw(const float* __restrict__ X, const float* __restrict__ sW,
                    const float* __restrict__ sb,
                    const float* __restrict__ agg, const float* __restrict__ stats,
                    const float* __restrict__ g, const float* __restrict__ be,
                    float* __restrict__ out, int n, int nrb){
  const int G = 256 / C;
  const int TR = G * RPT;
  __shared__ float4 Xs[TR*16];
  int tid = threadIdx.x;
  int c = tid % C;
  int rg = tid / C;
  float w[64];
  #pragma unroll
  for(int k = 0; k < 64; k++) w[k] = sW[k*C + c];
  float bc = sb[c];
  float invn = 1.0f / n;
  float m   = stats[c]*invn;
  float var = stats[C+c]*invn - m*m;
  float rsq = rsqrtf(var + BNEPS);
  float gc = g[c], bec = be[c];
  const float4* X4 = reinterpret_cast<const float4*>(X);
  for(int rb = blockIdx.x; rb < nrb; rb += gridDim.x){
    int r0 = rb*TR;
    __syncthreads();
    for(int t = tid; t < TR*16; t += 256){
      int r = r0 + (t >> 4);
      Xs[t] = (r < n) ? X4[(size_t)r*16 + (t & 15)] : make_float4(0.f,0.f,0.f,0.f);
    }
    __syncthreads();
    #pragma unroll
    for(int rr = 0; rr < RPT; rr++){
      int lr = rg*RPT + rr;
      int row = r0 + lr;
      if(row >= n) continue;
      float acc = bc;
      #pragma unroll
      for(int kq = 0; kq < 16; kq++){
        float4 xv = Xs[lr*16 + kq];
        acc = fmaf(xv.x, w[4*kq+0], acc);
        acc = fmaf(xv.y, w[4*kq+1], acc);
        acc = fmaf(xv.z, w[4*kq+2], acc);
        acc = fmaf(xv.w, w[4*kq+3], acc);
      }
      float a = agg[(size_t)row*C + c];
      out[(size_t)row*C + c] = fmaxf((a-m)*rsq*gc + bec, 0.f) + acc;
    }
  }
}

// ---------------- small GEMMs / BN ----------------

// P[n,4] @ W[4,64] + b -> H[n,64]; fused stats
__global__ void k_gemm_in4_st(const float* __restrict__ P, const float* __restrict__ W,
                              const float* __restrict__ bias, float* __restrict__ H,
                              float* __restrict__ stats, int n){
  int tid = threadIdx.x;
  int c = tid & 63;
  float s = 0.f, s2 = 0.f;
  for(int i = blockIdx.x*4 + (tid >> 6); i < n; i += gridDim.x*4){
    float4 xr = *reinterpret_cast<const float4*>(P + (size_t)i*4);
    float acc = bias[c] + xr.x*W[c] + xr.y*W[64+c] + xr.z*W[128+c] + xr.w*W[192+c];
    H[(size_t)i*64 + c] = acc;
    s += acc; s2 += acc*acc;
  }
  __shared__ float rs[256], rs2[256];
  rs[tid] = s; rs2[tid] = s2;
  __syncthreads();
  if(tid < 64){
    float a = rs[tid] + rs[tid+64] + rs[tid+128] + rs[tid+192];
    float a2 = rs2[tid] + rs2[tid+64] + rs2[tid+128] + rs2[tid+192];
    atomicAdd(&stats[tid], a);
    atomicAdd(&stats[64+tid], a2);
  }
}

// float4-vectorized: out = relu(bn(agg)) + add    (C channels, C%4==0)
template<int C>
__global__ void k_bn_add4(const float* __restrict__ agg, const float* __restrict__ stats,
                          const float* __restrict__ g, const float* __restrict__ be,
                          const float* __restrict__ add, float* __restrict__ out, int n){
  int idx = blockIdx.x*blockDim.x + threadIdx.x;    // over n*C/4
  if(idx >= n*(C/4)) return;
  int c = (idx % (C/4))*4;
  float invn = 1.0f / n;
  float4 sm = *reinterpret_cast<const float4*>(stats + c);
  float4 sq = *reinterpret_cast<const float4*>(stats + C + c);
  float4 g4 = *reinterpret_cast<const float4*>(g + c);
  float4 b4 = *reinterpret_cast<const float4*>(be + c);
  float4 a  = reinterpret_cast<const float4*>(agg)[idx];
  float4 ad = reinterpret_cast<const float4*>(add)[idx];
  float4 o;
  #define BN1(X) { float m = sm.X*invn; float v = sq.X*invn - m*m; \
    o.X = fmaxf((a.X-m)*rsqrtf(v+BNEPS)*g4.X + b4.X, 0.f) + ad.X; }
  BN1(x) BN1(y) BN1(z) BN1(w)
  #undef BN1
  reinterpret_cast<float4*>(out)[idx] = o;
}

// block1 epilogue, float4: out = relu(bn(agg)) + x[i,0:4]@sW + sb   (C=64)
__global__ void k_bn_sc4_v4(const float* __restrict__ agg, const float* __restrict__ stats,
                            const float* __restrict__ g, const float* __restrict__ be,
                            const float* __restrict__ X, const float* __restrict__ sW,
                            const float* __restrict__ sb, float* __restrict__ out, int n){
  int idx = blockIdx.x*blockDim.x + threadIdx.x;    // over n*16
  if(idx >= n*16) return;
  int i = idx >> 4;
  int c = (idx & 15)*4;
  float invn = 1.0f / n;
  float4 xr = *reinterpret_cast<const float4*>(X + (size_t)i*4);
  float4 s0 = *reinterpret_cast<const float4*>(sW + c);
  float4 s1 = *reinterpret_cast<const float4*>(sW + 64 + c);
  float4 s2 = *reinterpret_cast<const float4*>(sW + 128 + c);
  float4 s3 = *reinterpret_cast<const float4*>(sW + 192 + c);
  float4 sb4 = *reinterpret_cast<const float4*>(sb + c);
  float4 sm = *reinterpret_cast<const float4*>(stats + c);
  float4 sq = *reinterpret_cast<const float4*>(stats + 64 + c);
  float4 g4 = *reinterpret_cast<const float4*>(g + c);
  float4 b4 = *reinterpret_cast<const float4*>(be + c);
  float4 a  = reinterpret_cast<const float4*>(agg)[idx];
  float4 o;
  #define BN1(X) { float sc = xr.x*s0.X + xr.y*s1.X + xr.z*s2.X + xr.w*s3.X + sb4.X; \
    float m = sm.X*invn; float v = sq.X*invn - m*m; \
    o.X = fmaxf((a.X-m)*rsqrtf(v+BNEPS)*g4.X + b4.X, 0.f) + sc; }
  BN1(x) BN1(y) BN1(z) BN1(w)
  #undef BN1
  reinterpret_cast<float4*>(out)[idx] = o;
}

// ---------------- stats (head only) ----------------

template<int C>
__global__ void k_stats(const float* __restrict__ x, int n, float* __restrict__ stats){
  __shared__ float ss[256], ss2[256];
  int tid = threadIdx.x;
  const int rpb = 256 / C;
  int c = tid % C;
  int rsub = tid / C;
  float s = 0.f, s2 = 0.f;
  for(int i = blockIdx.x*rpb + rsub; i < n; i += gridDim.x*rpb){
    float v = x[(size_t)i*C + c];
    s += v; s2 += v*v;
  }
  ss[tid] = s; ss2[tid] = s2;
  __syncthreads();
  if(tid < C){
    float a = 0.f, a2 = 0.f;
    for(int j = tid; j < 256; j += C){ a += ss[j]; a2 += ss2[j]; }
    atomicAdd(&stats[c], a);
    atomicAdd(&stats[C+c], a2);
  }
}

// ---------------- pooling / head ----------------

__global__ void k_pool(const float* __restrict__ H, const int* __restrict__ batch,
                       float* __restrict__ z, int n){
  int b = blockIdx.x, c = threadIdx.x;
  int lo = 0, hi = n;
  while(lo < hi){ int mid = (lo+hi)>>1; if(batch[mid] <  b) lo = mid+1; else hi = mid; }
  int start = lo;
  hi = n;
  while(lo < hi){ int mid = (lo+hi)>>1; if(batch[mid] <  b+1) lo = mid+1; else hi = mid; }
  int end = lo;
  float s = 0.f, mx = -INFINITY;
  for(int i = start; i < end; i++){
    float v = H[(size_t)i*128 + c];
    s += v; mx = fmaxf(mx, v);
  }
  int cnt = end - start;
  z[b*256 + c]       = s / fmaxf((float)cnt, 1.f);
  z[b*256 + 128 + c] = mx;
}

__global__ void k_head1(const float* __restrict__ z, const float* __restrict__ fW1,
                        const float* __restrict__ fb1, float* __restrict__ zr, int B){
  int idx = blockIdx.x*blockDim.x + threadIdx.x;
  if(idx >= B*128) return;
  int b = idx >> 7, c = idx & 127;
  float acc = fb1[c];
  #pragma unroll 4
  for(int k = 0; k < 256; k++) acc = fmaf(z[b*256+k], fW1[k*128+c], acc);
  zr[idx] = acc;
}

__global__ void k_final(const float* __restrict__ zr, const float* __restrict__ stats,
                        const float* __restrict__ fg, const float* __restrict__ fbe,
                        const float* __restrict__ fW2, const float* __restrict__ fb2,
                        float* __restrict__ out, int B){
  __shared__ float red[128];
  int b = blockIdx.x, c = threadIdx.x;
  float invn = 1.0f / B;
  float m  = stats[c]*invn;
  float v  = stats[128+c]*invn - m*m;
  float rs = rsqrtf(v + BNEPS);
  float val = fmaxf((zr[b*128+c]-m)*rs*fg[c] + fbe[c], 0.f) * fW2[c];
  red[c] = val;
  __syncthreads();
  for(int s = 64; s > 0; s >>= 1){
    if(c < s) red[c] += red[c+s];
    __syncthreads();
  }
  if(c == 0) out[b] = red[0] + fb2[0];
}

// ---------------- launch ----------------

extern "C" void kernel_launch(void* const* d_in, const int* in_sizes, int n_in,
                              void* d_out, int out_size, void* d_ws, size_t ws_size,
                              hipStream_t stream){
  const float* x   = (const float*)d_in[0];
  const int*   ei  = (const int*)  d_in[1];
  const float* ew  = (const float*)d_in[2];
  const int*   bat = (const int*)  d_in[3];
  const float* W1  = (const float*)d_in[4];  const float* b1  = (const float*)d_in[5];
  const float* g1  = (const float*)d_in[6];  const float* be1 = (const float*)d_in[7];
  const float* sW1 = (const float*)d_in[8];  const float* sb1 = (const float*)d_in[9];
  const float* W2  = (const float*)d_in[10]; const float* b2  = (const float*)d_in[11];
  const float* g2  = (const float*)d_in[12]; const float* be2 = (const float*)d_in[13];
  const float* W3  = (const float*)d_in[14]; const float* b3  = (const float*)d_in[15];
  const float* g3  = (const float*)d_in[16]; const float* be3 = (const float*)d_in[17];
  const float* sW3 = (const float*)d_in[18]; const float* sb3 = (const float*)d_in[19];
  const float* fW1 = (const float*)d_in[20]; const float* fb1 = (const float*)d_in[21];
  const float* fg  = (const float*)d_in[22]; const float* fbe = (const float*)d_in[23];
  const float* fW2 = (const float*)d_in[24]; const float* fb2 = (const float*)d_in[25];
  float* out = (float*)d_out;

  const int n = in_sizes[0] / 4;
  const int E = in_sizes[2];
  const int B = out_size;          // 512
  const int* src = ei;
  const int* dst = ei + E;

  auto GB = [](long long t){ return (int)((t + 255) / 256); };
  const int nscanb = (n + 255) / 256;   // <= 256 required for k_scan2

  float* ws = (float*)d_ws;
  size_t off = 0;
  auto alloc = [&](size_t cnt)->float*{ float* p = ws + off; off += (cnt + 63) & ~size_t(63); return p; };

  const size_t npad = ((size_t)n + 63) & ~size_t(63);
  float* dis   = alloc(n);
  float* bufA  = alloc((size_t)n * 64);
  float* hbuf  = alloc((size_t)n * 128);   // P buffers / block3 output
  float* agg   = alloc((size_t)n * 128);
  float* z     = alloc((size_t)B * 256);
  float* zr    = alloc((size_t)B * 128);
  float* zreg  = alloc(npad + 1024);       // cnt (n ints) + 4x256 stats, zeroed together
  int*   cnt   = (int*)zreg;
  float* st1 = zreg + npad, *st2 = st1 + 256, *st3 = st2 + 256, *stH = st3 + 256;
  int*   rowptr = (int*)alloc(n + 1);
  int*   bsum   = (int*)alloc(256);
  int2*  erec   = (int2*)alloc((size_t)E * 2);

  // ---- CSR build (sorted by dst), norm folded into erec.w ----
  k_fill<<<GB(npad + 1024),256,0,stream>>>(zreg, (int)(npad + 1024), 0.f);
  k_count<<<GB(E),256,0,stream>>>(cnt, dst, E);
  k_scan1<<<nscanb,256,0,stream>>>(cnt, rowptr, bsum, n);   // also re-zeroes cnt
  k_scan2<<<1,256,0,stream>>>(bsum, nscanb);
  k_scan3<<<GB(n),256,0,stream>>>(rowptr, bsum, n, E);
  k_scatter2<<<GB(E),256,0,stream>>>(src, dst, ew, rowptr, cnt, erec, E);
  k_degdis<<<GB(n),256,0,stream>>>(erec, rowptr, dis, n);
  k_mknorm<<<GB(n),256,0,stream>>>(erec, rowptr, dis, n);

  const int nrb64  = (n + 31) / 32;   // TR=32 for C=64
  const int nrb128 = (n + 15) / 16;   // TR=16 for C=128
  auto grid_for = [](int nrb){ return nrb < 2048 ? nrb : 2048; };

  // ---- block1: P1=gather(x)[n,4]; agg=P1@W1+b1 (+stats); BN+ReLU+(x@sW1+sb1) -> bufA
  float* P = hbuf;
  k_gather4<<<GB(n),256,0,stream>>>(x, dis, rowptr, erec, P, n);
  k_gemm_in4_st<<<512,256,0,stream>>>(P, W1, b1, agg, st1, n);
  k_bn_sc4_v4<<<GB((long long)n*16),256,0,stream>>>(agg, st1, g1, be1, x, sW1, sb1, bufA, n);

  // ---- block2: P2=gather(bufA)[n,64]; agg=P2@W2+b2 (+stats); BN+ReLU+identity -> bufA
  k_gather<64><<<(n+3)/4,256,0,stream>>>(bufA, dis, rowptr, erec, P, n);
  k_gemm_rw<64,8><<<grid_for(nrb64),256,0,stream>>>(P, W2, b2, agg, st2, n, nrb64);
  k_bn_add4<64><<<GB((long long)n*16),256,0,stream>>>(agg, st2, g2, be2, bufA, bufA, n);

  // ---- block3: P3=gather(bufA)[n,64]; agg=P3@W3+b3 [n,128] (+stats);
  //      out = relu(bn(agg)) + bufA@sW3+sb3 -> hbuf
  k_gather<64><<<(n+3)/4,256,0,stream>>>(bufA, dis, rowptr, erec, P, n);
  k_gemm_rw<128,8><<<grid_for(nrb128),256,0,stream>>>(P, W3, b3, agg, st3, n, nrb128);
  k_gemm_bnsc_rw<128,8><<<grid_for(nrb128),256,0,stream>>>(bufA, sW3, sb3, agg, st3, g3, be3, hbuf, n, nrb128);

  // ---- pooling + head ----
  k_pool<<<B,128,0,stream>>>(hbuf, bat, z, n);
  k_head1<<<GB((long long)B*128),256,0,stream>>>(z, fW1, fb1, zr, B);
  k_stats<128><<<64,256,0,stream>>>(zr, B, stH);
  k_final<<<B,128,0,stream>>>(zr, stH, fg, fbe, fW2, fb2, out, B);
}